// Round 3
// baseline (4999.572 us; speedup 1.0000x reference)
//
#include <hip/hip_runtime.h>
#include <hip/hip_bf16.h>
#include <math.h>

// Problem constants (LightGFormer): B=16, N=512, D=256, L=4, H=8, dk=32, Dff=1024
#define BDIM 16
#define NSEQ 512
#define DMODEL 256
#define NLAYER 4
#define NHEAD 8
#define DK 32
#define DFF 1024
#define BN (BDIM * NSEQ)          // 8192 tokens
#define ND (NSEQ * DMODEL)        // 131072

// ---------------------------------------------------------------------------
// x = input + pos ; xv = input_v + pos   (all fp32)
// ---------------------------------------------------------------------------
__global__ void add_pos_kernel(const float* __restrict__ in,
                               const float* __restrict__ inv,
                               const float* __restrict__ pos,
                               float* __restrict__ x, float* __restrict__ xv,
                               int total) {
    int i = blockIdx.x * blockDim.x + threadIdx.x;
    if (i < total) {
        float pe = pos[i % ND];
        x[i]  = in[i]  + pe;
        xv[i] = inv[i] + pe;
    }
}

// ---------------------------------------------------------------------------
// Generic tiled GEMM: C[M,N] = A[M,K] @ W[K,N] + bias (all fp32)
// optional exact GELU epilogue. BM=BN=64, BK=16, 16x16 threads, 4x4 microtile.
// ---------------------------------------------------------------------------
__global__ __launch_bounds__(256) void gemm_bias_kernel(
        const float* __restrict__ A, const float* __restrict__ W,
        const float* __restrict__ bias, float* __restrict__ C,
        int M, int K, int N, int gelu_flag) {
    const int BM = 64, BNt = 64, BK = 16;
    __shared__ float As[BK][BM];
    __shared__ float Bs[BK][BNt];
    int tx = threadIdx.x, ty = threadIdx.y;
    int tid = ty * 16 + tx;
    int rowBase = blockIdx.y * BM;
    int colBase = blockIdx.x * BNt;
    float acc[4][4] = {};
    for (int kt = 0; kt < K; kt += BK) {
        for (int i = tid; i < BM * BK; i += 256) {
            int m = i >> 4, kk = i & 15;
            As[kk][m] = A[(size_t)(rowBase + m) * K + kt + kk];
        }
        for (int i = tid; i < BK * BNt; i += 256) {
            int kk = i >> 6, n = i & 63;
            Bs[kk][n] = W[(size_t)(kt + kk) * N + colBase + n];
        }
        __syncthreads();
#pragma unroll
        for (int kk = 0; kk < BK; kk++) {
            float a[4], b[4];
#pragma unroll
            for (int i = 0; i < 4; i++) a[i] = As[kk][ty + 16 * i];
#pragma unroll
            for (int j = 0; j < 4; j++) b[j] = Bs[kk][tx + 16 * j];
#pragma unroll
            for (int i = 0; i < 4; i++)
#pragma unroll
                for (int j = 0; j < 4; j++)
                    acc[i][j] += a[i] * b[j];
        }
        __syncthreads();
    }
#pragma unroll
    for (int i = 0; i < 4; i++) {
        int row = rowBase + ty + 16 * i;
#pragma unroll
        for (int j = 0; j < 4; j++) {
            int col = colBase + tx + 16 * j;
            float c = acc[i][j] + bias[col];
            if (gelu_flag) c = 0.5f * c * (1.f + erff(c * 0.70710678118654752f));
            C[(size_t)row * N + col] = c;
        }
    }
}

// ---------------------------------------------------------------------------
// Attention: one wave (64 threads) per (b, h, q) row.
// q,k,v are (B,N,D) fp32 with head-major inner layout [h*32+d].
// ---------------------------------------------------------------------------
__global__ __launch_bounds__(64) void attn_kernel(
        const float* __restrict__ q, const float* __restrict__ k,
        const float* __restrict__ v, float* __restrict__ o,
        const int* __restrict__ mask, int use_mask) {
    int bid = blockIdx.x;
    int qi = bid & (NSEQ - 1);
    int h  = (bid >> 9) & (NHEAD - 1);
    int b  = bid >> 12;
    int tid = threadIdx.x;

    __shared__ float qs[DK];
    __shared__ float p[NSEQ];
    __shared__ float oh[DK];

    const float* qrow = q + ((size_t)(b * NSEQ + qi)) * DMODEL + h * DK;
    if (tid < DK) qs[tid] = qrow[tid];
    __syncthreads();

    const float scale = 0.17677669529663687f; // 1/sqrt(32)
    for (int kk = tid; kk < NSEQ; kk += 64) {
        const float* krow = k + ((size_t)(b * NSEQ + kk)) * DMODEL + h * DK;
        float s = 0.f;
#pragma unroll
        for (int d0 = 0; d0 < DK; d0++) s += qs[d0] * krow[d0];
        s *= scale;
        if (use_mask && mask[qi * NSEQ + kk]) s = -INFINITY;
        p[kk] = s;
    }
    __syncthreads();

    float m = -INFINITY;
    for (int kk = tid; kk < NSEQ; kk += 64) m = fmaxf(m, p[kk]);
#pragma unroll
    for (int off = 32; off; off >>= 1) m = fmaxf(m, __shfl_xor(m, off));

    float sum = 0.f;
    for (int kk = tid; kk < NSEQ; kk += 64) {
        float s = p[kk];
        // guard: if the whole row is masked (m == -inf), emit 0 not NaN
        float e = (m > -INFINITY && s > -INFINITY) ? __expf(s - m) : 0.f;
        p[kk] = e;
        sum += e;
    }
#pragma unroll
    for (int off = 32; off; off >>= 1) sum += __shfl_xor(sum, off);
    float invs = (sum > 0.f) ? 1.f / sum : 0.f;
    __syncthreads();

    // phase 2: dims 0..31, two half-waves each cover half the keys
    int d0 = tid & 31;
    int half = tid >> 5;
    float acc = 0.f;
    const float* vbase = v + ((size_t)b * NSEQ) * DMODEL + h * DK + d0;
    int k0 = half * (NSEQ / 2);
    for (int kk = k0; kk < k0 + NSEQ / 2; kk++)
        acc += p[kk] * vbase[(size_t)kk * DMODEL];
    if (half) oh[d0] = acc;
    __syncthreads();
    if (!half)
        o[((size_t)(b * NSEQ + qi)) * DMODEL + h * DK + d0] = (acc + oh[d0]) * invs;
}

// ---------------------------------------------------------------------------
// out = LayerNorm(a + r) * g + be   (fp32, one block per token, D=256)
// ---------------------------------------------------------------------------
__global__ __launch_bounds__(256) void add_ln_kernel(
        const float* __restrict__ a, const float* __restrict__ r,
        const float* __restrict__ g, const float* __restrict__ be,
        float* __restrict__ out) {
    int t = blockIdx.x;
    int d = threadIdx.x;
    size_t idx = (size_t)t * DMODEL + d;
    float v = a[idx] + r[idx];
    float s = v, s2 = v * v;
#pragma unroll
    for (int off = 32; off; off >>= 1) {
        s  += __shfl_xor(s, off);
        s2 += __shfl_xor(s2, off);
    }
    __shared__ float ws1[4], ws2[4];
    int wid = d >> 6;
    if ((d & 63) == 0) { ws1[wid] = s; ws2[wid] = s2; }
    __syncthreads();
    s  = ws1[0] + ws1[1] + ws1[2] + ws1[3];
    s2 = ws2[0] + ws2[1] + ws2[2] + ws2[3];
    float mean = s * (1.f / DMODEL);
    float var = s2 * (1.f / DMODEL) - mean * mean;
    float rstd = rsqrtf(var + 1e-5f);
    out[idx] = (v - mean) * rstd * g[d] + be[d];
}

// Final LN: out = LayerNorm(x) * gf + bf   (fp32 out)
__global__ __launch_bounds__(256) void final_ln_kernel(
        const float* __restrict__ a,
        const float* __restrict__ g, const float* __restrict__ be,
        float* __restrict__ out) {
    int t = blockIdx.x;
    int d = threadIdx.x;
    size_t idx = (size_t)t * DMODEL + d;
    float v = a[idx];
    float s = v, s2 = v * v;
#pragma unroll
    for (int off = 32; off; off >>= 1) {
        s  += __shfl_xor(s, off);
        s2 += __shfl_xor(s2, off);
    }
    __shared__ float ws1[4], ws2[4];
    int wid = d >> 6;
    if ((d & 63) == 0) { ws1[wid] = s; ws2[wid] = s2; }
    __syncthreads();
    s  = ws1[0] + ws1[1] + ws1[2] + ws1[3];
    s2 = ws2[0] + ws2[1] + ws2[2] + ws2[3];
    float mean = s * (1.f / DMODEL);
    float var = s2 * (1.f / DMODEL) - mean * mean;
    float rstd = rsqrtf(var + 1e-5f);
    out[idx] = (v - mean) * rstd * g[d] + be[d];
}

// ---------------------------------------------------------------------------
extern "C" void kernel_launch(void* const* d_in, const int* in_sizes, int n_in,
                              void* d_out, int out_size, void* d_ws, size_t ws_size,
                              hipStream_t stream) {
    const float* input  = (const float*)d_in[0];
    const float* inputv = (const float*)d_in[1];
    const float* pos    = (const float*)d_in[2];
    const float* Wq = (const float*)d_in[3];
    const float* bq = (const float*)d_in[4];
    const float* Wk = (const float*)d_in[5];
    const float* bk = (const float*)d_in[6];
    const float* Wv = (const float*)d_in[7];
    const float* bv = (const float*)d_in[8];
    const float* Wo = (const float*)d_in[9];
    const float* bo = (const float*)d_in[10];
    const float* W1 = (const float*)d_in[11];
    const float* b1 = (const float*)d_in[12];
    const float* W2 = (const float*)d_in[13];
    const float* b2 = (const float*)d_in[14];
    const float* g1 = (const float*)d_in[15];
    const float* be1 = (const float*)d_in[16];
    const float* g2 = (const float*)d_in[17];
    const float* be2 = (const float*)d_in[18];
    const float* gf = (const float*)d_in[19];
    const float* bff = (const float*)d_in[20];
    const int* mask = (const int*)d_in[21];

    float* out = (float*)d_out;

    // Workspace layout (fp32), total 7*TOK = 56 MB:
    //   x  : TOK   (persistent residual stream)
    //   xv : TOK   (persistent value stream)
    //   pj : TOK   (Wo / FFN2 output)
    //   R  : 4*TOK (union: {qb,kb,vb,ab} during attention | hb during FFN)
    float* ws = (float*)d_ws;
    const size_t TOK = (size_t)BN * DMODEL;  // 2,097,152
    float* x  = ws;
    float* xv = x + TOK;
    float* pj = xv + TOK;
    float* R  = pj + TOK;
    float* qb = R;
    float* kb = R + TOK;
    float* vb = R + 2 * TOK;
    float* ab = R + 3 * TOK;
    float* hb = R;            // 4*TOK, overlaps qb..ab (dead by FFN time)

    // x = input + pos ; xv = input_v + pos
    add_pos_kernel<<<(int)((TOK + 255) / 256), 256, 0, stream>>>(
        input, inputv, pos, x, xv, (int)TOK);

    dim3 tb(16, 16);
    for (int i = 0; i < NLAYER; i++) {
        const float* Wq_i = Wq + (size_t)i * DMODEL * DMODEL;
        const float* Wk_i = Wk + (size_t)i * DMODEL * DMODEL;
        const float* Wv_i = Wv + (size_t)i * DMODEL * DMODEL;
        const float* Wo_i = Wo + (size_t)i * DMODEL * DMODEL;
        const float* W1_i = W1 + (size_t)i * DMODEL * DFF;
        const float* W2_i = W2 + (size_t)i * (DFF / 2) * (DMODEL / 2);

        // Q/K from x, V from xv
        gemm_bias_kernel<<<dim3(DMODEL / 64, BN / 64), tb, 0, stream>>>(
            x, Wq_i, bq + i * DMODEL, qb, BN, DMODEL, DMODEL, 0);
        gemm_bias_kernel<<<dim3(DMODEL / 64, BN / 64), tb, 0, stream>>>(
            x, Wk_i, bk + i * DMODEL, kb, BN, DMODEL, DMODEL, 0);
        gemm_bias_kernel<<<dim3(DMODEL / 64, BN / 64), tb, 0, stream>>>(
            xv, Wv_i, bv + i * DMODEL, vb, BN, DMODEL, DMODEL, 0);

        attn_kernel<<<BDIM * NHEAD * NSEQ, 64, 0, stream>>>(
            qb, kb, vb, ab, mask, (i & 1));

        gemm_bias_kernel<<<dim3(DMODEL / 64, BN / 64), tb, 0, stream>>>(
            ab, Wo_i, bo + i * DMODEL, pj, BN, DMODEL, DMODEL, 0);

        add_ln_kernel<<<BN, DMODEL, 0, stream>>>(
            x, pj, g1 + i * DMODEL, be1 + i * DMODEL, x);

        // FFN: h = gelu(x @ W1 + b1)   (hb overlaps dead qb..ab)
        gemm_bias_kernel<<<dim3(DFF / 64, BN / 64), tb, 0, stream>>>(
            x, W1_i, b1 + i * DFF, hb, BN, DMODEL, DFF, 1);
        // grouped second linear == plain GEMM: (2*BN, 512) @ (512, 128)
        gemm_bias_kernel<<<dim3((DMODEL / 2) / 64, (2 * BN) / 64), tb, 0, stream>>>(
            hb, W2_i, b2 + i * (DMODEL / 2), pj, 2 * BN, DFF / 2, DMODEL / 2, 0);

        add_ln_kernel<<<BN, DMODEL, 0, stream>>>(
            x, pj, g2 + i * DMODEL, be2 + i * DMODEL, x);
    }

    final_ln_kernel<<<BN, DMODEL, 0, stream>>>(x, gf, bff, out);
}

// Round 4
// 2750.707 us; speedup vs baseline: 1.8176x; 1.8176x over previous
//
#include <hip/hip_runtime.h>
#include <hip/hip_bf16.h>
#include <math.h>

// Problem constants (LightGFormer): B=16, N=512, D=256, L=4, H=8, dk=32, Dff=1024
#define BDIM 16
#define NSEQ 512
#define DMODEL 256
#define NLAYER 4
#define NHEAD 8
#define DK 32
#define DFF 1024
#define BN (BDIM * NSEQ)          // 8192 tokens
#define ND (NSEQ * DMODEL)        // 131072

// ---------------------------------------------------------------------------
// x = input + pos ; xv = input_v + pos   (all fp32)
// ---------------------------------------------------------------------------
__global__ void add_pos_kernel(const float* __restrict__ in,
                               const float* __restrict__ inv,
                               const float* __restrict__ pos,
                               float* __restrict__ x, float* __restrict__ xv,
                               int total) {
    int i = blockIdx.x * blockDim.x + threadIdx.x;
    if (i < total) {
        float pe = pos[i % ND];
        x[i]  = in[i]  + pe;
        xv[i] = inv[i] + pe;
    }
}

// ---------------------------------------------------------------------------
// Generic tiled GEMM: C[M,N] = A[M,K] @ W[K,N] + bias (all fp32)
// optional exact GELU epilogue. BM=BN=64, BK=16, 16x16 threads, 4x4 microtile.
// ---------------------------------------------------------------------------
__global__ __launch_bounds__(256) void gemm_bias_kernel(
        const float* __restrict__ A, const float* __restrict__ W,
        const float* __restrict__ bias, float* __restrict__ C,
        int M, int K, int N, int gelu_flag) {
    const int BM = 64, BNt = 64, BK = 16;
    __shared__ float As[BK][BM];
    __shared__ float Bs[BK][BNt];
    int tx = threadIdx.x, ty = threadIdx.y;
    int tid = ty * 16 + tx;
    int rowBase = blockIdx.y * BM;
    int colBase = blockIdx.x * BNt;
    float acc[4][4] = {};
    for (int kt = 0; kt < K; kt += BK) {
        for (int i = tid; i < BM * BK; i += 256) {
            int m = i >> 4, kk = i & 15;
            As[kk][m] = A[(size_t)(rowBase + m) * K + kt + kk];
        }
        for (int i = tid; i < BK * BNt; i += 256) {
            int kk = i >> 6, n = i & 63;
            Bs[kk][n] = W[(size_t)(kt + kk) * N + colBase + n];
        }
        __syncthreads();
#pragma unroll
        for (int kk = 0; kk < BK; kk++) {
            float a[4], b[4];
#pragma unroll
            for (int i = 0; i < 4; i++) a[i] = As[kk][ty + 16 * i];
#pragma unroll
            for (int j = 0; j < 4; j++) b[j] = Bs[kk][tx + 16 * j];
#pragma unroll
            for (int i = 0; i < 4; i++)
#pragma unroll
                for (int j = 0; j < 4; j++)
                    acc[i][j] += a[i] * b[j];
        }
        __syncthreads();
    }
#pragma unroll
    for (int i = 0; i < 4; i++) {
        int row = rowBase + ty + 16 * i;
#pragma unroll
        for (int j = 0; j < 4; j++) {
            int col = colBase + tx + 16 * j;
            float c = acc[i][j] + bias[col];
            if (gelu_flag) c = 0.5f * c * (1.f + erff(c * 0.70710678118654752f));
            C[(size_t)row * N + col] = c;
        }
    }
}

// ---------------------------------------------------------------------------
// Tiled attention: one block = one (b, h, half-of-queries) tile.
// 256 threads; each lane owns ONE q row (Q row, O acc, score chunk in regs).
// K^h staged in LDS once (64 KB), broadcast-read by all 4 waves.
// V read from global with wave-broadcast float4 loads (L1/L2 resident).
// Online softmax over 32-key chunks.
// ---------------------------------------------------------------------------
__global__ __launch_bounds__(256) void attn_tile_kernel(
        const float* __restrict__ q, const float* __restrict__ k,
        const float* __restrict__ v, float* __restrict__ o,
        const int* __restrict__ mask, int use_mask) {
    int bid = blockIdx.x;
    int tile = bid & 1;
    int h = (bid >> 1) & (NHEAD - 1);
    int b = bid >> 4;
    int tid = threadIdx.x;

    __shared__ float Ks[NSEQ][DK];   // 64 KB

    // stage K^h: 512 rows x 32 floats, float4-vectorized
    const float* kbase = k + ((size_t)b * NSEQ) * DMODEL + h * DK;
    for (int i = tid; i < NSEQ * 8; i += 256) {
        int row = i >> 3, c4 = i & 7;
        float4 val = *(const float4*)(kbase + (size_t)row * DMODEL + c4 * 4);
        *(float4*)&Ks[row][c4 * 4] = val;
    }

    // this lane's q row into registers
    int qi = tile * 256 + tid;
    const float* qrow = q + ((size_t)(b * NSEQ + qi)) * DMODEL + h * DK;
    float qr[DK];
#pragma unroll
    for (int c4 = 0; c4 < 8; c4++) {
        float4 val = *(const float4*)(qrow + c4 * 4);
        qr[c4 * 4 + 0] = val.x; qr[c4 * 4 + 1] = val.y;
        qr[c4 * 4 + 2] = val.z; qr[c4 * 4 + 3] = val.w;
    }
    __syncthreads();

    const float scale = 0.17677669529663687f; // 1/sqrt(32)
    const float* vbase = v + ((size_t)b * NSEQ) * DMODEL + h * DK;
    const int* mrow = mask + (size_t)qi * NSEQ;

    float o_acc[DK] = {};
    float m_run = -INFINITY, l_run = 0.f;

    for (int c0 = 0; c0 < NSEQ; c0 += 32) {
        float s[32];
#pragma unroll
        for (int j = 0; j < 32; j++) {
            int kk = c0 + j;
            float dot = 0.f;
#pragma unroll
            for (int c4 = 0; c4 < 8; c4++) {
                float4 kv = *(const float4*)&Ks[kk][c4 * 4];  // broadcast, conflict-free
                dot += qr[c4 * 4 + 0] * kv.x + qr[c4 * 4 + 1] * kv.y
                     + qr[c4 * 4 + 2] * kv.z + qr[c4 * 4 + 3] * kv.w;
            }
            s[j] = dot * scale;
            if (use_mask && mrow[kk]) s[j] = -INFINITY;
        }
        float cmax = s[0];
#pragma unroll
        for (int j = 1; j < 32; j++) cmax = fmaxf(cmax, s[j]);
        float mnew = fmaxf(m_run, cmax);
        if (mnew == -INFINITY) continue;   // whole row masked so far
        float corr = __expf(m_run - mnew); // m_run=-inf -> 0
        l_run *= corr;
#pragma unroll
        for (int d = 0; d < DK; d++) o_acc[d] *= corr;
#pragma unroll
        for (int j = 0; j < 32; j++) {
            int kk = c0 + j;
            float p = __expf(s[j] - mnew);  // s=-inf -> 0
            l_run += p;
            const float4* vr = (const float4*)(vbase + (size_t)kk * DMODEL);
#pragma unroll
            for (int c4 = 0; c4 < 8; c4++) {
                float4 vv = vr[c4];         // wave-broadcast global read
                o_acc[c4 * 4 + 0] += p * vv.x;
                o_acc[c4 * 4 + 1] += p * vv.y;
                o_acc[c4 * 4 + 2] += p * vv.z;
                o_acc[c4 * 4 + 3] += p * vv.w;
            }
        }
        m_run = mnew;
    }

    float invl = (l_run > 0.f) ? 1.f / l_run : 0.f;
    float* orow = o + ((size_t)(b * NSEQ + qi)) * DMODEL + h * DK;
#pragma unroll
    for (int c4 = 0; c4 < 8; c4++) {
        float4 val;
        val.x = o_acc[c4 * 4 + 0] * invl;
        val.y = o_acc[c4 * 4 + 1] * invl;
        val.z = o_acc[c4 * 4 + 2] * invl;
        val.w = o_acc[c4 * 4 + 3] * invl;
        *(float4*)(orow + c4 * 4) = val;
    }
}

// ---------------------------------------------------------------------------
// out = LayerNorm(a + r) * g + be   (fp32, one block per token, D=256)
// ---------------------------------------------------------------------------
__global__ __launch_bounds__(256) void add_ln_kernel(
        const float* __restrict__ a, const float* __restrict__ r,
        const float* __restrict__ g, const float* __restrict__ be,
        float* __restrict__ out) {
    int t = blockIdx.x;
    int d = threadIdx.x;
    size_t idx = (size_t)t * DMODEL + d;
    float v = a[idx] + r[idx];
    float s = v, s2 = v * v;
#pragma unroll
    for (int off = 32; off; off >>= 1) {
        s  += __shfl_xor(s, off);
        s2 += __shfl_xor(s2, off);
    }
    __shared__ float ws1[4], ws2[4];
    int wid = d >> 6;
    if ((d & 63) == 0) { ws1[wid] = s; ws2[wid] = s2; }
    __syncthreads();
    s  = ws1[0] + ws1[1] + ws1[2] + ws1[3];
    s2 = ws2[0] + ws2[1] + ws2[2] + ws2[3];
    float mean = s * (1.f / DMODEL);
    float var = s2 * (1.f / DMODEL) - mean * mean;
    float rstd = rsqrtf(var + 1e-5f);
    out[idx] = (v - mean) * rstd * g[d] + be[d];
}

// Final LN: out = LayerNorm(x) * gf + bf   (fp32 out)
__global__ __launch_bounds__(256) void final_ln_kernel(
        const float* __restrict__ a,
        const float* __restrict__ g, const float* __restrict__ be,
        float* __restrict__ out) {
    int t = blockIdx.x;
    int d = threadIdx.x;
    size_t idx = (size_t)t * DMODEL + d;
    float v = a[idx];
    float s = v, s2 = v * v;
#pragma unroll
    for (int off = 32; off; off >>= 1) {
        s  += __shfl_xor(s, off);
        s2 += __shfl_xor(s2, off);
    }
    __shared__ float ws1[4], ws2[4];
    int wid = d >> 6;
    if ((d & 63) == 0) { ws1[wid] = s; ws2[wid] = s2; }
    __syncthreads();
    s  = ws1[0] + ws1[1] + ws1[2] + ws1[3];
    s2 = ws2[0] + ws2[1] + ws2[2] + ws2[3];
    float mean = s * (1.f / DMODEL);
    float var = s2 * (1.f / DMODEL) - mean * mean;
    float rstd = rsqrtf(var + 1e-5f);
    out[idx] = (v - mean) * rstd * g[d] + be[d];
}

// ---------------------------------------------------------------------------
extern "C" void kernel_launch(void* const* d_in, const int* in_sizes, int n_in,
                              void* d_out, int out_size, void* d_ws, size_t ws_size,
                              hipStream_t stream) {
    const float* input  = (const float*)d_in[0];
    const float* inputv = (const float*)d_in[1];
    const float* pos    = (const float*)d_in[2];
    const float* Wq = (const float*)d_in[3];
    const float* bq = (const float*)d_in[4];
    const float* Wk = (const float*)d_in[5];
    const float* bk = (const float*)d_in[6];
    const float* Wv = (const float*)d_in[7];
    const float* bv = (const float*)d_in[8];
    const float* Wo = (const float*)d_in[9];
    const float* bo = (const float*)d_in[10];
    const float* W1 = (const float*)d_in[11];
    const float* b1 = (const float*)d_in[12];
    const float* W2 = (const float*)d_in[13];
    const float* b2 = (const float*)d_in[14];
    const float* g1 = (const float*)d_in[15];
    const float* be1 = (const float*)d_in[16];
    const float* g2 = (const float*)d_in[17];
    const float* be2 = (const float*)d_in[18];
    const float* gf = (const float*)d_in[19];
    const float* bff = (const float*)d_in[20];
    const int* mask = (const int*)d_in[21];

    float* out = (float*)d_out;

    // Workspace layout (fp32), total 7*TOK = 56 MB:
    //   x  : TOK   (persistent residual stream)
    //   xv : TOK   (persistent value stream)
    //   pj : TOK   (Wo / FFN2 output)
    //   R  : 4*TOK (union: {qb,kb,vb,ab} during attention | hb during FFN)
    float* ws = (float*)d_ws;
    const size_t TOK = (size_t)BN * DMODEL;  // 2,097,152
    float* x  = ws;
    float* xv = x + TOK;
    float* pj = xv + TOK;
    float* R  = pj + TOK;
    float* qb = R;
    float* kb = R + TOK;
    float* vb = R + 2 * TOK;
    float* ab = R + 3 * TOK;
    float* hb = R;            // 4*TOK, overlaps qb..ab (dead by FFN time)

    // x = input + pos ; xv = input_v + pos
    add_pos_kernel<<<(int)((TOK + 255) / 256), 256, 0, stream>>>(
        input, inputv, pos, x, xv, (int)TOK);

    dim3 tb(16, 16);
    for (int i = 0; i < NLAYER; i++) {
        const float* Wq_i = Wq + (size_t)i * DMODEL * DMODEL;
        const float* Wk_i = Wk + (size_t)i * DMODEL * DMODEL;
        const float* Wv_i = Wv + (size_t)i * DMODEL * DMODEL;
        const float* Wo_i = Wo + (size_t)i * DMODEL * DMODEL;
        const float* W1_i = W1 + (size_t)i * DMODEL * DFF;
        const float* W2_i = W2 + (size_t)i * (DFF / 2) * (DMODEL / 2);

        // Q/K from x, V from xv
        gemm_bias_kernel<<<dim3(DMODEL / 64, BN / 64), tb, 0, stream>>>(
            x, Wq_i, bq + i * DMODEL, qb, BN, DMODEL, DMODEL, 0);
        gemm_bias_kernel<<<dim3(DMODEL / 64, BN / 64), tb, 0, stream>>>(
            x, Wk_i, bk + i * DMODEL, kb, BN, DMODEL, DMODEL, 0);
        gemm_bias_kernel<<<dim3(DMODEL / 64, BN / 64), tb, 0, stream>>>(
            xv, Wv_i, bv + i * DMODEL, vb, BN, DMODEL, DMODEL, 0);

        // tiled attention: grid = B * H * 2 = 256 blocks (one per CU)
        attn_tile_kernel<<<BDIM * NHEAD * 2, 256, 0, stream>>>(
            qb, kb, vb, ab, mask, (i & 1));

        gemm_bias_kernel<<<dim3(DMODEL / 64, BN / 64), tb, 0, stream>>>(
            ab, Wo_i, bo + i * DMODEL, pj, BN, DMODEL, DMODEL, 0);

        add_ln_kernel<<<BN, DMODEL, 0, stream>>>(
            x, pj, g1 + i * DMODEL, be1 + i * DMODEL, x);

        // FFN: h = gelu(x @ W1 + b1)   (hb overlaps dead qb..ab)
        gemm_bias_kernel<<<dim3(DFF / 64, BN / 64), tb, 0, stream>>>(
            x, W1_i, b1 + i * DFF, hb, BN, DMODEL, DFF, 1);
        // grouped second linear == plain GEMM: (2*BN, 512) @ (512, 128)
        gemm_bias_kernel<<<dim3((DMODEL / 2) / 64, (2 * BN) / 64), tb, 0, stream>>>(
            hb, W2_i, b2 + i * (DMODEL / 2), pj, 2 * BN, DFF / 2, DMODEL / 2, 0);

        add_ln_kernel<<<BN, DMODEL, 0, stream>>>(
            x, pj, g2 + i * DMODEL, be2 + i * DMODEL, x);
    }

    final_ln_kernel<<<BN, DMODEL, 0, stream>>>(x, gf, bff, out);
}

// Round 5
// 1260.622 us; speedup vs baseline: 3.9660x; 2.1820x over previous
//
#include <hip/hip_runtime.h>
#include <hip/hip_bf16.h>
#include <math.h>

// Problem constants (LightGFormer): B=16, N=512, D=256, L=4, H=8, dk=32, Dff=1024
#define BDIM 16
#define NSEQ 512
#define DMODEL 256
#define NLAYER 4
#define NHEAD 8
#define DK 32
#define DFF 1024
#define BN (BDIM * NSEQ)          // 8192 tokens
#define ND (NSEQ * DMODEL)        // 131072

typedef __bf16 bf16x8 __attribute__((ext_vector_type(8)));
typedef float floatx4 __attribute__((ext_vector_type(4)));

// RNE float->bf16 bits (matches __float2bfloat16 for finite values)
static __device__ __forceinline__ unsigned short f2bf(float f) {
    unsigned u = __float_as_uint(f);
    unsigned r = (u + 0x7FFFu + ((u >> 16) & 1u)) >> 16;
    return (unsigned short)r;
}

// ---------------------------------------------------------------------------
// Weight preconvert: src fp32 [L,K,N] -> dst bf16 [L,N,K] (transposed)
// ---------------------------------------------------------------------------
__global__ void conv_w_kernel(const float* __restrict__ src,
                              unsigned short* __restrict__ dst,
                              int K, int N, int total) {
    int i = blockIdx.x * 256 + threadIdx.x;
    if (i >= total) return;
    int kn = K * N;
    int l = i / kn;
    int rem = i - l * kn;
    int k = rem / N;
    int n = rem - k * N;
    dst[(size_t)l * kn + (size_t)n * K + k] = f2bf(src[i]);
}

// mask (int 512x512) -> bitmask (512 x 16 uint32)
__global__ void conv_mask_kernel(const int* __restrict__ mask,
                                 unsigned* __restrict__ bits) {
    int w = blockIdx.x * blockDim.x + threadIdx.x; // 0..8191
    int r = w >> 4, wi = w & 15;
    const int* src = mask + r * NSEQ + wi * 32;
    unsigned acc = 0;
#pragma unroll
    for (int j = 0; j < 32; j++) acc |= (src[j] != 0 ? 1u : 0u) << j;
    bits[w] = acc;
}

// ---------------------------------------------------------------------------
// x = input + pos (fp32 + bf16) ; xv = input_v + pos (bf16 only)
// ---------------------------------------------------------------------------
__global__ void add_pos_kernel(const float* __restrict__ in,
                               const float* __restrict__ inv,
                               const float* __restrict__ pos,
                               float* __restrict__ x,
                               unsigned short* __restrict__ xb,
                               unsigned short* __restrict__ xvb,
                               int total) {
    int i = blockIdx.x * blockDim.x + threadIdx.x;
    if (i < total) {
        float pe = pos[i % ND];
        float a = in[i] + pe;
        float b = inv[i] + pe;
        x[i] = a;
        xb[i] = f2bf(a);
        xvb[i] = f2bf(b);
    }
}

// ---------------------------------------------------------------------------
// MFMA GEMM: C[M,N] = A[M,K](bf16) @ Bt[N,K](bf16)^T + bias(fp32)
// 128x128 tile, 4 waves x (4x4) 16x16x32 MFMA, BK=32. act=1 -> exact GELU.
// Writes fp32 (Cf) and/or bf16 (Cb).
// ---------------------------------------------------------------------------
__global__ __launch_bounds__(256) void gemm_mfma_kernel(
        const unsigned short* __restrict__ A,
        const unsigned short* __restrict__ Bt,
        const float* __restrict__ bias,
        float* __restrict__ Cf, unsigned short* __restrict__ Cb,
        int M, int K, int N, int act) {
    __shared__ unsigned short As[128 * 32];
    __shared__ unsigned short Bs[128 * 32];
    int tid = threadIdx.x;
    int wave = tid >> 6, lane = tid & 63;
    int rowBase = blockIdx.y * 128, colBase = blockIdx.x * 128;
    int m0w = (wave & 1) * 64, n0w = (wave >> 1) * 64;
    int lr = lane & 15, quad = lane >> 4;

    floatx4 acc[4][4];
#pragma unroll
    for (int mi = 0; mi < 4; mi++)
#pragma unroll
        for (int nj = 0; nj < 4; nj++) acc[mi][nj] = (floatx4)0.0f;

    for (int kt = 0; kt < K; kt += 32) {
#pragma unroll
        for (int t = 0; t < 2; t++) {
            int idx = tid * 2 + t;          // 0..511
            int row = idx >> 2;             // 0..127
            int kv8 = (idx & 3) * 8;        // 0,8,16,24
            *(uint4*)&As[row * 32 + kv8] =
                *(const uint4*)(A + (size_t)(rowBase + row) * K + kt + kv8);
            *(uint4*)&Bs[row * 32 + kv8] =
                *(const uint4*)(Bt + (size_t)(colBase + row) * K + kt + kv8);
        }
        __syncthreads();
        bf16x8 af[4], bfr[4];
#pragma unroll
        for (int mi = 0; mi < 4; mi++)
            af[mi] = *(const bf16x8*)&As[(m0w + mi * 16 + lr) * 32 + quad * 8];
#pragma unroll
        for (int nj = 0; nj < 4; nj++)
            bfr[nj] = *(const bf16x8*)&Bs[(n0w + nj * 16 + lr) * 32 + quad * 8];
#pragma unroll
        for (int mi = 0; mi < 4; mi++)
#pragma unroll
            for (int nj = 0; nj < 4; nj++)
                acc[mi][nj] = __builtin_amdgcn_mfma_f32_16x16x32_bf16(
                    af[mi], bfr[nj], acc[mi][nj], 0, 0, 0);
        __syncthreads();
    }

#pragma unroll
    for (int mi = 0; mi < 4; mi++) {
#pragma unroll
        for (int r = 0; r < 4; r++) {
            int grow = rowBase + m0w + mi * 16 + quad * 4 + r;
#pragma unroll
            for (int nj = 0; nj < 4; nj++) {
                int gcol = colBase + n0w + nj * 16 + lr;
                float c = acc[mi][nj][r] + bias[gcol];
                if (act) c = 0.5f * c * (1.f + erff(c * 0.70710678118654752f));
                size_t off = (size_t)grow * N + gcol;
                if (Cf) Cf[off] = c;
                if (Cb) Cb[off] = f2bf(c);
            }
        }
    }
}

// ---------------------------------------------------------------------------
// Tiled attention: one block per (b, h, half-of-queries). 256 threads,
// lane owns one q row. K^h in LDS (64KB); V chunk-staged double-buffered
// (2x8KB). Mask as precomputed bitmask in registers. Output bf16.
// ---------------------------------------------------------------------------
__global__ __launch_bounds__(256) void attn_tile_kernel(
        const float* __restrict__ q, const float* __restrict__ k,
        const float* __restrict__ v, unsigned short* __restrict__ o,
        const unsigned* __restrict__ mbits_g, int use_mask) {
    int bid = blockIdx.x;
    int tile = bid & 1;
    int h = (bid >> 1) & (NHEAD - 1);
    int b = bid >> 4;
    int tid = threadIdx.x;

    __shared__ float Ks[NSEQ][DK];     // 64 KB
    __shared__ float Vs[2][64][DK];    // 16 KB

    const float* kbase = k + ((size_t)b * NSEQ) * DMODEL + h * DK;
    const float* vbase = v + ((size_t)b * NSEQ) * DMODEL + h * DK;
    for (int i = tid; i < NSEQ * 8; i += 256) {
        int row = i >> 3, c4 = i & 7;
        *(float4*)&Ks[row][c4 * 4] =
            *(const float4*)(kbase + (size_t)row * DMODEL + c4 * 4);
    }
    for (int i = tid; i < 64 * 8; i += 256) {
        int row = i >> 3, c4 = i & 7;
        *(float4*)&Vs[0][row][c4 * 4] =
            *(const float4*)(vbase + (size_t)row * DMODEL + c4 * 4);
    }

    int qi = tile * 256 + tid;
    const float* qrow = q + ((size_t)(b * NSEQ + qi)) * DMODEL + h * DK;
    float qr[DK];
#pragma unroll
    for (int c4 = 0; c4 < 8; c4++) {
        float4 t = *(const float4*)(qrow + c4 * 4);
        qr[c4 * 4 + 0] = t.x; qr[c4 * 4 + 1] = t.y;
        qr[c4 * 4 + 2] = t.z; qr[c4 * 4 + 3] = t.w;
    }
    unsigned mbits[16];
#pragma unroll
    for (int w = 0; w < 16; w++) mbits[w] = 0;
    if (use_mask) {
        const unsigned* mr = mbits_g + (size_t)qi * 16;
#pragma unroll
        for (int w = 0; w < 16; w++) mbits[w] = mr[w];
    }
    __syncthreads();

    const float scale = 0.17677669529663687f; // 1/sqrt(32)
    float o_acc[DK] = {};
    float m_run = -INFINITY, l_run = 0.f;

    for (int c0 = 0; c0 < NSEQ; c0 += 64) {
        int cur = (c0 >> 6) & 1, nxt = cur ^ 1;
        if (c0 + 64 < NSEQ) {
            for (int i = tid; i < 64 * 8; i += 256) {
                int row = i >> 3, c4 = i & 7;
                *(float4*)&Vs[nxt][row][c4 * 4] =
                    *(const float4*)(vbase + (size_t)(c0 + 64 + row) * DMODEL + c4 * 4);
            }
        }
#pragma unroll
        for (int half = 0; half < 64; half += 32) {
            float s[32];
#pragma unroll
            for (int j = 0; j < 32; j++) {
                int kk = c0 + half + j;
                float dot = 0.f;
#pragma unroll
                for (int c4 = 0; c4 < 8; c4++) {
                    float4 kv = *(const float4*)&Ks[kk][c4 * 4]; // broadcast
                    dot += qr[c4 * 4 + 0] * kv.x + qr[c4 * 4 + 1] * kv.y
                         + qr[c4 * 4 + 2] * kv.z + qr[c4 * 4 + 3] * kv.w;
                }
                s[j] = dot * scale;
                if (use_mask && ((mbits[kk >> 5] >> (kk & 31)) & 1)) s[j] = -INFINITY;
            }
            float cmax = s[0];
#pragma unroll
            for (int j = 1; j < 32; j++) cmax = fmaxf(cmax, s[j]);
            float mnew = fmaxf(m_run, cmax);
            if (mnew == -INFINITY) continue;
            float corr = __expf(m_run - mnew);
            l_run *= corr;
#pragma unroll
            for (int d = 0; d < DK; d++) o_acc[d] *= corr;
#pragma unroll
            for (int j = 0; j < 32; j++) {
                float p = __expf(s[j] - mnew);
                l_run += p;
                const float* vrow = &Vs[cur][half + j][0];
#pragma unroll
                for (int c4 = 0; c4 < 8; c4++) {
                    float4 vv = *(const float4*)(vrow + c4 * 4); // broadcast
                    o_acc[c4 * 4 + 0] += p * vv.x;
                    o_acc[c4 * 4 + 1] += p * vv.y;
                    o_acc[c4 * 4 + 2] += p * vv.z;
                    o_acc[c4 * 4 + 3] += p * vv.w;
                }
            }
            m_run = mnew;
        }
        __syncthreads();
    }

    float invl = (l_run > 0.f) ? 1.f / l_run : 0.f;
    unsigned short ob[DK];
#pragma unroll
    for (int d = 0; d < DK; d++) ob[d] = f2bf(o_acc[d] * invl);
    unsigned short* orow = o + ((size_t)(b * NSEQ + qi)) * DMODEL + h * DK;
#pragma unroll
    for (int c8 = 0; c8 < 4; c8++)
        *(uint4*)(orow + c8 * 8) = *(const uint4*)(ob + c8 * 8);
}

// ---------------------------------------------------------------------------
// out = LayerNorm(a + r) * g + be   (fp32 out + bf16 copy), one block/token
// ---------------------------------------------------------------------------
__global__ __launch_bounds__(256) void add_ln_kernel(
        const float* __restrict__ a, const float* __restrict__ r,
        const float* __restrict__ g, const float* __restrict__ be,
        float* __restrict__ out, unsigned short* __restrict__ outb) {
    int t = blockIdx.x;
    int d = threadIdx.x;
    size_t idx = (size_t)t * DMODEL + d;
    float v = a[idx] + r[idx];
    float s = v, s2 = v * v;
#pragma unroll
    for (int off = 32; off; off >>= 1) {
        s  += __shfl_xor(s, off);
        s2 += __shfl_xor(s2, off);
    }
    __shared__ float ws1[4], ws2[4];
    int wid = d >> 6;
    if ((d & 63) == 0) { ws1[wid] = s; ws2[wid] = s2; }
    __syncthreads();
    s  = ws1[0] + ws1[1] + ws1[2] + ws1[3];
    s2 = ws2[0] + ws2[1] + ws2[2] + ws2[3];
    float mean = s * (1.f / DMODEL);
    float var = s2 * (1.f / DMODEL) - mean * mean;
    float rstd = rsqrtf(var + 1e-5f);
    float res = (v - mean) * rstd * g[d] + be[d];
    out[idx] = res;
    outb[idx] = f2bf(res);
}

// Final LN: out = LayerNorm(x) * gf + bf (fp32)
__global__ __launch_bounds__(256) void final_ln_kernel(
        const float* __restrict__ a,
        const float* __restrict__ g, const float* __restrict__ be,
        float* __restrict__ out) {
    int t = blockIdx.x;
    int d = threadIdx.x;
    size_t idx = (size_t)t * DMODEL + d;
    float v = a[idx];
    float s = v, s2 = v * v;
#pragma unroll
    for (int off = 32; off; off >>= 1) {
        s  += __shfl_xor(s, off);
        s2 += __shfl_xor(s2, off);
    }
    __shared__ float ws1[4], ws2[4];
    int wid = d >> 6;
    if ((d & 63) == 0) { ws1[wid] = s; ws2[wid] = s2; }
    __syncthreads();
    s  = ws1[0] + ws1[1] + ws1[2] + ws1[3];
    s2 = ws2[0] + ws2[1] + ws2[2] + ws2[3];
    float mean = s * (1.f / DMODEL);
    float var = s2 * (1.f / DMODEL) - mean * mean;
    float rstd = rsqrtf(var + 1e-5f);
    out[idx] = (v - mean) * rstd * g[d] + be[d];
}

// ---------------------------------------------------------------------------
extern "C" void kernel_launch(void* const* d_in, const int* in_sizes, int n_in,
                              void* d_out, int out_size, void* d_ws, size_t ws_size,
                              hipStream_t stream) {
    const float* input  = (const float*)d_in[0];
    const float* inputv = (const float*)d_in[1];
    const float* pos    = (const float*)d_in[2];
    const float* Wq = (const float*)d_in[3];
    const float* bq = (const float*)d_in[4];
    const float* Wk = (const float*)d_in[5];
    const float* bk = (const float*)d_in[6];
    const float* Wv = (const float*)d_in[7];
    const float* bv = (const float*)d_in[8];
    const float* Wo = (const float*)d_in[9];
    const float* bo = (const float*)d_in[10];
    const float* W1 = (const float*)d_in[11];
    const float* b1 = (const float*)d_in[12];
    const float* W2 = (const float*)d_in[13];
    const float* b2 = (const float*)d_in[14];
    const float* g1 = (const float*)d_in[15];
    const float* be1 = (const float*)d_in[16];
    const float* g2 = (const float*)d_in[17];
    const float* be2 = (const float*)d_in[18];
    const float* gf = (const float*)d_in[19];
    const float* bff = (const float*)d_in[20];
    const int* mask = (const int*)d_in[21];

    float* out = (float*)d_out;

    // Workspace layout (bytes); total < 57.1 MB (prior rounds used 56 MB OK)
    char* wsb = (char*)d_ws;
    float* x_f  = (float*)(wsb + ((size_t)0 << 20));
    float* pj_f = (float*)(wsb + ((size_t)8 << 20));
    float* qb_f = (float*)(wsb + ((size_t)16 << 20));
    float* kb_f = (float*)(wsb + ((size_t)24 << 20));
    float* vb_f = (float*)(wsb + ((size_t)32 << 20));
    unsigned short* x_b  = (unsigned short*)(wsb + ((size_t)40 << 20));
    unsigned short* xv_b = (unsigned short*)(wsb + ((size_t)44 << 20));
    unsigned short* ab_b = (unsigned short*)(wsb + ((size_t)48 << 20));
    unsigned short* h_b  = (unsigned short*)(wsb + ((size_t)16 << 20)); // alias qb+kb (dead in FFN)
    unsigned short* wqT = (unsigned short*)(wsb + ((size_t)52 << 20));
    unsigned short* wkT = wqT + (size_t)4 * 65536;
    unsigned short* wvT = wkT + (size_t)4 * 65536;
    unsigned short* woT = wvT + (size_t)4 * 65536;
    unsigned short* w1T = woT + (size_t)4 * 65536;   // 4 x 262144
    unsigned short* w2T = w1T + (size_t)4 * 262144;  // 4 x 65536
    unsigned* mbits = (unsigned*)(wsb + ((size_t)57 << 20)); // 32 KB

    const size_t TOK = (size_t)BN * DMODEL;  // 2,097,152

    // --- preconversions ---
    int tqk = 4 * 256 * 256;
    conv_w_kernel<<<(tqk + 255) / 256, 256, 0, stream>>>(Wq, wqT, 256, 256, tqk);
    conv_w_kernel<<<(tqk + 255) / 256, 256, 0, stream>>>(Wk, wkT, 256, 256, tqk);
    conv_w_kernel<<<(tqk + 255) / 256, 256, 0, stream>>>(Wv, wvT, 256, 256, tqk);
    conv_w_kernel<<<(tqk + 255) / 256, 256, 0, stream>>>(Wo, woT, 256, 256, tqk);
    int tw1 = 4 * 256 * 1024;
    conv_w_kernel<<<(tw1 + 255) / 256, 256, 0, stream>>>(W1, w1T, 256, 1024, tw1);
    int tw2 = 4 * 512 * 128;
    conv_w_kernel<<<(tw2 + 255) / 256, 256, 0, stream>>>(W2, w2T, 512, 128, tw2);
    conv_mask_kernel<<<8192 / 256, 256, 0, stream>>>(mask, mbits);

    add_pos_kernel<<<(int)((TOK + 255) / 256), 256, 0, stream>>>(
        input, inputv, pos, x_f, x_b, xv_b, (int)TOK);

    for (int i = 0; i < NLAYER; i++) {
        const unsigned short* WqT_i = wqT + (size_t)i * 65536;
        const unsigned short* WkT_i = wkT + (size_t)i * 65536;
        const unsigned short* WvT_i = wvT + (size_t)i * 65536;
        const unsigned short* WoT_i = woT + (size_t)i * 65536;
        const unsigned short* W1T_i = w1T + (size_t)i * 262144;
        const unsigned short* W2T_i = w2T + (size_t)i * 65536;

        // Q/K from x, V from xv   (M=8192, K=256, N=256)
        gemm_mfma_kernel<<<dim3(2, 64), 256, 0, stream>>>(
            x_b, WqT_i, bq + i * DMODEL, qb_f, nullptr, BN, DMODEL, DMODEL, 0);
        gemm_mfma_kernel<<<dim3(2, 64), 256, 0, stream>>>(
            x_b, WkT_i, bk + i * DMODEL, kb_f, nullptr, BN, DMODEL, DMODEL, 0);
        gemm_mfma_kernel<<<dim3(2, 64), 256, 0, stream>>>(
            xv_b, WvT_i, bv + i * DMODEL, vb_f, nullptr, BN, DMODEL, DMODEL, 0);

        attn_tile_kernel<<<BDIM * NHEAD * 2, 256, 0, stream>>>(
            qb_f, kb_f, vb_f, ab_b, mbits, (i & 1));

        gemm_mfma_kernel<<<dim3(2, 64), 256, 0, stream>>>(
            ab_b, WoT_i, bo + i * DMODEL, pj_f, nullptr, BN, DMODEL, DMODEL, 0);

        add_ln_kernel<<<BN, DMODEL, 0, stream>>>(
            x_f, pj_f, g1 + i * DMODEL, be1 + i * DMODEL, x_f, x_b);

        // FFN1: h = gelu(x @ W1 + b1), bf16 out only (M=8192,K=256,N=1024)
        gemm_mfma_kernel<<<dim3(8, 64), 256, 0, stream>>>(
            x_b, W1T_i, b1 + i * DFF, nullptr, h_b, BN, DMODEL, DFF, 1);
        // FFN2 grouped == plain GEMM (M=16384, K=512, N=128)
        gemm_mfma_kernel<<<dim3(1, 128), 256, 0, stream>>>(
            h_b, W2T_i, b2 + i * (DMODEL / 2), pj_f, nullptr,
            2 * BN, DFF / 2, DMODEL / 2, 0);

        add_ln_kernel<<<BN, DMODEL, 0, stream>>>(
            x_f, pj_f, g2 + i * DMODEL, be2 + i * DMODEL, x_f, x_b);
    }

    final_ln_kernel<<<BN, DMODEL, 0, stream>>>(x_f, gf, bff, out);
}

// Round 6
// 715.681 us; speedup vs baseline: 6.9858x; 1.7614x over previous
//
#include <hip/hip_runtime.h>
#include <hip/hip_bf16.h>
#include <math.h>

// Problem constants (LightGFormer): B=16, N=512, D=256, L=4, H=8, dk=32, Dff=1024
#define BDIM 16
#define NSEQ 512
#define DMODEL 256
#define NLAYER 4
#define NHEAD 8
#define DK 32
#define DFF 1024
#define BN (BDIM * NSEQ)          // 8192 tokens
#define ND (NSEQ * DMODEL)        // 131072

typedef __bf16 bf16x8 __attribute__((ext_vector_type(8)));
typedef float floatx4 __attribute__((ext_vector_type(4)));
typedef unsigned short ushort_t;

// RNE float->bf16 bits
static __device__ __forceinline__ unsigned short f2bf(float f) {
    unsigned u = __float_as_uint(f);
    unsigned r = (u + 0x7FFFu + ((u >> 16) & 1u)) >> 16;
    return (unsigned short)r;
}

// ---------------------------------------------------------------------------
// Weight preconvert: src fp32 [L,K,N] -> dst bf16 [L,N,K] (transposed)
// ---------------------------------------------------------------------------
__global__ void conv_w_kernel(const float* __restrict__ src,
                              unsigned short* __restrict__ dst,
                              int K, int N, int total) {
    int i = blockIdx.x * 256 + threadIdx.x;
    if (i >= total) return;
    int kn = K * N;
    int l = i / kn;
    int rem = i - l * kn;
    int k = rem / N;
    int n = rem - k * N;
    dst[(size_t)l * kn + (size_t)n * K + k] = f2bf(src[i]);
}

// mask (int 512x512) -> bitmask (512 x 16 uint32); bit=1 -> -inf
__global__ void conv_mask_kernel(const int* __restrict__ mask,
                                 unsigned* __restrict__ bits) {
    int w = blockIdx.x * blockDim.x + threadIdx.x; // 0..8191
    int r = w >> 4, wi = w & 15;
    const int* src = mask + r * NSEQ + wi * 32;
    unsigned acc = 0;
#pragma unroll
    for (int j = 0; j < 32; j++) acc |= (src[j] != 0 ? 1u : 0u) << j;
    bits[w] = acc;
}

// ---------------------------------------------------------------------------
// x = input + pos (fp32 + bf16) ; xv = input_v + pos (bf16 only)
// ---------------------------------------------------------------------------
__global__ void add_pos_kernel(const float* __restrict__ in,
                               const float* __restrict__ inv,
                               const float* __restrict__ pos,
                               float* __restrict__ x,
                               unsigned short* __restrict__ xb,
                               unsigned short* __restrict__ xvb,
                               int total) {
    int i = blockIdx.x * blockDim.x + threadIdx.x;
    if (i < total) {
        float pe = pos[i % ND];
        float a = in[i] + pe;
        float b = inv[i] + pe;
        x[i] = a;
        xb[i] = f2bf(a);
        xvb[i] = f2bf(b);
    }
}

// ---------------------------------------------------------------------------
// MFMA GEMM: C[M,N] = A[M,K](bf16) @ Bt[N,K](bf16)^T + bias(fp32)
// 128x128 tile, 4 waves x (4x4) 16x16x32 MFMA, BK=32. act=1 -> exact GELU.
// hb=1 -> bf16 output in head-blocked layout [(row/512)*8 + col/32][row%512][col%32]
// ---------------------------------------------------------------------------
__global__ __launch_bounds__(256) void gemm_mfma_kernel(
        const unsigned short* __restrict__ A,
        const unsigned short* __restrict__ Bt,
        const float* __restrict__ bias,
        float* __restrict__ Cf, unsigned short* __restrict__ Cb,
        int M, int K, int N, int act, int hb) {
    __shared__ unsigned short As[128 * 32];
    __shared__ unsigned short Bs[128 * 32];
    int tid = threadIdx.x;
    int wave = tid >> 6, lane = tid & 63;
    int rowBase = blockIdx.y * 128, colBase = blockIdx.x * 128;
    int m0w = (wave & 1) * 64, n0w = (wave >> 1) * 64;
    int lr = lane & 15, quad = lane >> 4;

    floatx4 acc[4][4];
#pragma unroll
    for (int mi = 0; mi < 4; mi++)
#pragma unroll
        for (int nj = 0; nj < 4; nj++) acc[mi][nj] = (floatx4)0.0f;

    for (int kt = 0; kt < K; kt += 32) {
#pragma unroll
        for (int t = 0; t < 2; t++) {
            int idx = tid * 2 + t;
            int row = idx >> 2;
            int kv8 = (idx & 3) * 8;
            *(uint4*)&As[row * 32 + kv8] =
                *(const uint4*)(A + (size_t)(rowBase + row) * K + kt + kv8);
            *(uint4*)&Bs[row * 32 + kv8] =
                *(const uint4*)(Bt + (size_t)(colBase + row) * K + kt + kv8);
        }
        __syncthreads();
        bf16x8 af[4], bfr[4];
#pragma unroll
        for (int mi = 0; mi < 4; mi++)
            af[mi] = *(const bf16x8*)&As[(m0w + mi * 16 + lr) * 32 + quad * 8];
#pragma unroll
        for (int nj = 0; nj < 4; nj++)
            bfr[nj] = *(const bf16x8*)&Bs[(n0w + nj * 16 + lr) * 32 + quad * 8];
#pragma unroll
        for (int mi = 0; mi < 4; mi++)
#pragma unroll
            for (int nj = 0; nj < 4; nj++)
                acc[mi][nj] = __builtin_amdgcn_mfma_f32_16x16x32_bf16(
                    af[mi], bfr[nj], acc[mi][nj], 0, 0, 0);
        __syncthreads();
    }

#pragma unroll
    for (int mi = 0; mi < 4; mi++) {
#pragma unroll
        for (int r = 0; r < 4; r++) {
            int grow = rowBase + m0w + mi * 16 + quad * 4 + r;
#pragma unroll
            for (int nj = 0; nj < 4; nj++) {
                int gcol = colBase + n0w + nj * 16 + lr;
                float c = acc[mi][nj][r] + bias[gcol];
                if (act) c = 0.5f * c * (1.f + erff(c * 0.70710678118654752f));
                if (hb) {
                    size_t off = ((size_t)((grow >> 9) * 8 + (gcol >> 5)) << 14)
                               + (size_t)(grow & 511) * 32 + (gcol & 31);
                    Cb[off] = f2bf(c);
                } else {
                    size_t off = (size_t)grow * N + gcol;
                    if (Cf) Cf[off] = c;
                    if (Cb) Cb[off] = f2bf(c);
                }
            }
        }
    }
}

// ---------------------------------------------------------------------------
// MFMA attention. Grid = B*H*8 (q-groups of 64); 256 threads = 4 waves,
// each wave owns 16 q-columns. Computes S^T = K Q^T per 16x16 tile (one
// 16x16x32 MFMA, full dk), online softmax over kk via 4-lane shuffles,
// then O^T += V^T P with P converted in-register to the PV B-fragment
// (virtual K-order chosen so NO transpose / LDS round-trip is needed).
// q,k,v bf16 head-blocked [(b*8+h)*512 + kk]*32 + d. Output token-major bf16.
// ---------------------------------------------------------------------------
#define VTS 520  // Vt row stride (pad 512+8 to break bank conflicts)
__global__ __launch_bounds__(256) void attn_mfma_kernel(
        const unsigned short* __restrict__ q, const unsigned short* __restrict__ k,
        const unsigned short* __restrict__ v, unsigned short* __restrict__ o,
        const unsigned* __restrict__ mbits_g, int use_mask) {
    int bid = blockIdx.x;
    int qg = bid & 7, h = (bid >> 3) & 7, b = bid >> 6;
    int tid = threadIdx.x;

    __shared__ unsigned short Ks[NSEQ * DK];   // 32 KB, [kk][d]
    __shared__ unsigned short Vt[DK * VTS];    // 32.5 KB, [d][kk]

    const unsigned short* kbase = k + (size_t)(b * 8 + h) * (NSEQ * DK);
    const unsigned short* vbase = v + (size_t)(b * 8 + h) * (NSEQ * DK);

    // stage K (fully coalesced copy)
    for (int c = tid; c < NSEQ * DK / 8; c += 256)
        ((uint4*)Ks)[c] = ((const uint4*)kbase)[c];
    // stage V transposed
#pragma unroll
    for (int r = 0; r < 2; r++) {
        int kk = tid + r * 256;
        unsigned short tmp[32];
        *(uint4*)&tmp[0]  = *(const uint4*)(vbase + (size_t)kk * 32);
        *(uint4*)&tmp[8]  = *(const uint4*)(vbase + (size_t)kk * 32 + 8);
        *(uint4*)&tmp[16] = *(const uint4*)(vbase + (size_t)kk * 32 + 16);
        *(uint4*)&tmp[24] = *(const uint4*)(vbase + (size_t)kk * 32 + 24);
#pragma unroll
        for (int d = 0; d < 32; d++) Vt[d * VTS + kk] = tmp[d];
    }

    int wave = tid >> 6, lane = tid & 63, l16 = lane & 15, quad = lane >> 4;
    int qbase = qg * 64 + wave * 16;

    // Q B-fragment: lane holds Q[q=qbase+l16][d=quad*8+j]
    bf16x8 qf = *(const bf16x8*)(q + ((size_t)(b * 8 + h) * NSEQ + qbase + l16) * 32 + quad * 8);

    unsigned mw[16];
    if (use_mask) {
        const uint4* mr = (const uint4*)(mbits_g + (size_t)(qbase + l16) * 16);
#pragma unroll
        for (int w = 0; w < 4; w++) *(uint4*)&mw[w * 4] = mr[w];
    } else {
#pragma unroll
        for (int w = 0; w < 16; w++) mw[w] = 0;
    }
    __syncthreads();

    floatx4 oT0 = (floatx4)0.f, oT1 = (floatx4)0.f;  // O^T[d=quad*4+r(+16)][q=l16]
    float m_run = -INFINITY, l_part = 0.f;
    const float scale = 0.17677669529663687f; // 1/sqrt(32)

#pragma unroll
    for (int c = 0; c < 16; c++) {
        int kkb = c * 32;
        // QK^T: S^T tiles (kk 16 each), A=K-frag, B=Q-frag
        bf16x8 k0 = *(const bf16x8*)&Ks[(kkb + l16) * 32 + quad * 8];
        bf16x8 k1 = *(const bf16x8*)&Ks[(kkb + 16 + l16) * 32 + quad * 8];
        floatx4 s0 = __builtin_amdgcn_mfma_f32_16x16x32_bf16(k0, qf, (floatx4)0.f, 0, 0, 0);
        floatx4 s1 = __builtin_amdgcn_mfma_f32_16x16x32_bf16(k1, qf, (floatx4)0.f, 0, 0, 0);

        float sv[8];
#pragma unroll
        for (int r = 0; r < 4; r++) { sv[r] = s0[r] * scale; sv[4 + r] = s1[r] * scale; }
        if (use_mask) {
            unsigned wb = mw[c];
#pragma unroll
            for (int r = 0; r < 4; r++) {
                if ((wb >> (quad * 4 + r)) & 1) sv[r] = -INFINITY;
                if ((wb >> (16 + quad * 4 + r)) & 1) sv[4 + r] = -INFINITY;
            }
        }
        // online softmax (per q = l16; reduce across quads)
        float mx = sv[0];
#pragma unroll
        for (int j = 1; j < 8; j++) mx = fmaxf(mx, sv[j]);
        mx = fmaxf(mx, __shfl_xor(mx, 16));
        mx = fmaxf(mx, __shfl_xor(mx, 32));
        float mnew = fmaxf(m_run, mx);
        float corr = (m_run == mnew) ? 1.f : __expf(m_run - mnew);
        l_part *= corr;
        oT0 *= corr; oT1 *= corr;
        float p[8];
#pragma unroll
        for (int j = 0; j < 8; j++) {
            float e = __expf(sv[j] - mnew);
            p[j] = (sv[j] > -INFINITY) ? e : 0.f;
            l_part += p[j];
        }
        // P -> PV B-fragment directly: virtual key v=quad*8+j maps to actual
        // key kkb + (j<4 ? quad*4+j : 16+quad*4+(j-4)); V^T A-frag uses same order.
        union { bf16x8 v; unsigned short u[8]; } pf;
#pragma unroll
        for (int j = 0; j < 8; j++) pf.u[j] = f2bf(p[j]);

        bf16x8 av0, av1;
        ((uint2*)&av0)[0] = *(const uint2*)&Vt[l16 * VTS + kkb + quad * 4];
        ((uint2*)&av0)[1] = *(const uint2*)&Vt[l16 * VTS + kkb + 16 + quad * 4];
        ((uint2*)&av1)[0] = *(const uint2*)&Vt[(16 + l16) * VTS + kkb + quad * 4];
        ((uint2*)&av1)[1] = *(const uint2*)&Vt[(16 + l16) * VTS + kkb + 16 + quad * 4];

        oT0 = __builtin_amdgcn_mfma_f32_16x16x32_bf16(av0, pf.v, oT0, 0, 0, 0);
        oT1 = __builtin_amdgcn_mfma_f32_16x16x32_bf16(av1, pf.v, oT1, 0, 0, 0);
        m_run = mnew;
    }

    float l = l_part;
    l += __shfl_xor(l, 16);
    l += __shfl_xor(l, 32);
    float invl = (l > 0.f) ? 1.f / l : 0.f;

    unsigned short* orow = o + ((size_t)(b * NSEQ + qbase + l16)) * DMODEL + h * DK;
#pragma unroll
    for (int r = 0; r < 4; r++) {
        orow[quad * 4 + r]      = f2bf(oT0[r] * invl);
        orow[16 + quad * 4 + r] = f2bf(oT1[r] * invl);
    }
}

// ---------------------------------------------------------------------------
// out = LayerNorm(a + r) * g + be   (fp32 out + bf16 copy), one block/token
// ---------------------------------------------------------------------------
__global__ __launch_bounds__(256) void add_ln_kernel(
        const float* __restrict__ a, const float* __restrict__ r,
        const float* __restrict__ g, const float* __restrict__ be,
        float* __restrict__ out, unsigned short* __restrict__ outb) {
    int t = blockIdx.x;
    int d = threadIdx.x;
    size_t idx = (size_t)t * DMODEL + d;
    float v = a[idx] + r[idx];
    float s = v, s2 = v * v;
#pragma unroll
    for (int off = 32; off; off >>= 1) {
        s  += __shfl_xor(s, off);
        s2 += __shfl_xor(s2, off);
    }
    __shared__ float ws1[4], ws2[4];
    int wid = d >> 6;
    if ((d & 63) == 0) { ws1[wid] = s; ws2[wid] = s2; }
    __syncthreads();
    s  = ws1[0] + ws1[1] + ws1[2] + ws1[3];
    s2 = ws2[0] + ws2[1] + ws2[2] + ws2[3];
    float mean = s * (1.f / DMODEL);
    float var = s2 * (1.f / DMODEL) - mean * mean;
    float rstd = rsqrtf(var + 1e-5f);
    float res = (v - mean) * rstd * g[d] + be[d];
    out[idx] = res;
    outb[idx] = f2bf(res);
}

// Final LN: out = LayerNorm(x) * gf + bf (fp32)
__global__ __launch_bounds__(256) void final_ln_kernel(
        const float* __restrict__ a,
        const float* __restrict__ g, const float* __restrict__ be,
        float* __restrict__ out) {
    int t = blockIdx.x;
    int d = threadIdx.x;
    size_t idx = (size_t)t * DMODEL + d;
    float v = a[idx];
    float s = v, s2 = v * v;
#pragma unroll
    for (int off = 32; off; off >>= 1) {
        s  += __shfl_xor(s, off);
        s2 += __shfl_xor(s2, off);
    }
    __shared__ float ws1[4], ws2[4];
    int wid = d >> 6;
    if ((d & 63) == 0) { ws1[wid] = s; ws2[wid] = s2; }
    __syncthreads();
    s  = ws1[0] + ws1[1] + ws1[2] + ws1[3];
    s2 = ws2[0] + ws2[1] + ws2[2] + ws2[3];
    float mean = s * (1.f / DMODEL);
    float var = s2 * (1.f / DMODEL) - mean * mean;
    float rstd = rsqrtf(var + 1e-5f);
    out[idx] = (v - mean) * rstd * g[d] + be[d];
}

// ---------------------------------------------------------------------------
extern "C" void kernel_launch(void* const* d_in, const int* in_sizes, int n_in,
                              void* d_out, int out_size, void* d_ws, size_t ws_size,
                              hipStream_t stream) {
    const float* input  = (const float*)d_in[0];
    const float* inputv = (const float*)d_in[1];
    const float* pos    = (const float*)d_in[2];
    const float* Wq = (const float*)d_in[3];
    const float* bq = (const float*)d_in[4];
    const float* Wk = (const float*)d_in[5];
    const float* bk = (const float*)d_in[6];
    const float* Wv = (const float*)d_in[7];
    const float* bv = (const float*)d_in[8];
    const float* Wo = (const float*)d_in[9];
    const float* bo = (const float*)d_in[10];
    const float* W1 = (const float*)d_in[11];
    const float* b1 = (const float*)d_in[12];
    const float* W2 = (const float*)d_in[13];
    const float* b2 = (const float*)d_in[14];
    const float* g1 = (const float*)d_in[15];
    const float* be1 = (const float*)d_in[16];
    const float* g2 = (const float*)d_in[17];
    const float* be2 = (const float*)d_in[18];
    const float* gf = (const float*)d_in[19];
    const float* bff = (const float*)d_in[20];
    const int* mask = (const int*)d_in[21];

    float* out = (float*)d_out;

    // Workspace layout (bytes), total ~45.1 MB
    char* wsb = (char*)d_ws;
    float* x_f  = (float*)(wsb + ((size_t)0 << 20));            // 8 MB
    float* pj_f = (float*)(wsb + ((size_t)8 << 20));            // 8 MB
    unsigned short* x_b  = (unsigned short*)(wsb + ((size_t)16 << 20)); // 4 MB
    unsigned short* xv_b = (unsigned short*)(wsb + ((size_t)20 << 20)); // 4 MB
    unsigned short* qb_b = (unsigned short*)(wsb + ((size_t)24 << 20)); // 4 MB
    unsigned short* kb_b = (unsigned short*)(wsb + ((size_t)28 << 20)); // 4 MB
    unsigned short* vb_b = (unsigned short*)(wsb + ((size_t)32 << 20)); // 4 MB
    unsigned short* ab_b = (unsigned short*)(wsb + ((size_t)36 << 20)); // 4 MB
    unsigned short* h_b  = qb_b; // 16 MB alias over qb..ab (dead during FFN)
    unsigned short* wqT = (unsigned short*)(wsb + ((size_t)40 << 20));
    unsigned short* wkT = wqT + (size_t)4 * 65536;
    unsigned short* wvT = wkT + (size_t)4 * 65536;
    unsigned short* woT = wvT + (size_t)4 * 65536;
    unsigned short* w1T = woT + (size_t)4 * 65536;   // 4 x 262144
    unsigned short* w2T = w1T + (size_t)4 * 262144;  // 4 x 65536
    unsigned* mbits = (unsigned*)(wsb + ((size_t)45 << 20));    // 32 KB

    const size_t TOK = (size_t)BN * DMODEL;  // 2,097,152

    // --- preconversions ---
    int tqk = 4 * 256 * 256;
    conv_w_kernel<<<(tqk + 255) / 256, 256, 0, stream>>>(Wq, wqT, 256, 256, tqk);
    conv_w_kernel<<<(tqk + 255) / 256, 256, 0, stream>>>(Wk, wkT, 256, 256, tqk);
    conv_w_kernel<<<(tqk + 255) / 256, 256, 0, stream>>>(Wv, wvT, 256, 256, tqk);
    conv_w_kernel<<<(tqk + 255) / 256, 256, 0, stream>>>(Wo, woT, 256, 256, tqk);
    int tw1 = 4 * 256 * 1024;
    conv_w_kernel<<<(tw1 + 255) / 256, 256, 0, stream>>>(W1, w1T, 256, 1024, tw1);
    int tw2 = 4 * 512 * 128;
    conv_w_kernel<<<(tw2 + 255) / 256, 256, 0, stream>>>(W2, w2T, 512, 128, tw2);
    conv_mask_kernel<<<8192 / 256, 256, 0, stream>>>(mask, mbits);

    add_pos_kernel<<<(int)((TOK + 255) / 256), 256, 0, stream>>>(
        input, inputv, pos, x_f, x_b, xv_b, (int)TOK);

    for (int i = 0; i < NLAYER; i++) {
        const unsigned short* WqT_i = wqT + (size_t)i * 65536;
        const unsigned short* WkT_i = wkT + (size_t)i * 65536;
        const unsigned short* WvT_i = wvT + (size_t)i * 65536;
        const unsigned short* WoT_i = woT + (size_t)i * 65536;
        const unsigned short* W1T_i = w1T + (size_t)i * 262144;
        const unsigned short* W2T_i = w2T + (size_t)i * 65536;

        // Q/K from x, V from xv -> bf16 head-blocked
        gemm_mfma_kernel<<<dim3(2, 64), 256, 0, stream>>>(
            x_b, WqT_i, bq + i * DMODEL, nullptr, qb_b, BN, DMODEL, DMODEL, 0, 1);
        gemm_mfma_kernel<<<dim3(2, 64), 256, 0, stream>>>(
            x_b, WkT_i, bk + i * DMODEL, nullptr, kb_b, BN, DMODEL, DMODEL, 0, 1);
        gemm_mfma_kernel<<<dim3(2, 64), 256, 0, stream>>>(
            xv_b, WvT_i, bv + i * DMODEL, nullptr, vb_b, BN, DMODEL, DMODEL, 0, 1);

        attn_mfma_kernel<<<BDIM * NHEAD * 8, 256, 0, stream>>>(
            qb_b, kb_b, vb_b, ab_b, mbits, (i & 1));

        gemm_mfma_kernel<<<dim3(2, 64), 256, 0, stream>>>(
            ab_b, WoT_i, bo + i * DMODEL, pj_f, nullptr, BN, DMODEL, DMODEL, 0, 0);

        add_ln_kernel<<<BN, DMODEL, 0, stream>>>(
            x_f, pj_f, g1 + i * DMODEL, be1 + i * DMODEL, x_f, x_b);

        // FFN1: h = gelu(x @ W1 + b1), bf16 out (M=8192,K=256,N=1024)
        gemm_mfma_kernel<<<dim3(8, 64), 256, 0, stream>>>(
            x_b, W1T_i, b1 + i * DFF, nullptr, h_b, BN, DMODEL, DFF, 1, 0);
        // FFN2 grouped == plain GEMM (M=16384, K=512, N=128)
        gemm_mfma_kernel<<<dim3(1, 128), 256, 0, stream>>>(
            h_b, W2T_i, b2 + i * (DMODEL / 2), pj_f, nullptr,
            2 * BN, DFF / 2, DMODEL / 2, 0, 0);

        add_ln_kernel<<<BN, DMODEL, 0, stream>>>(
            x_f, pj_f, g2 + i * DMODEL, be2 + i * DMODEL, x_f, x_b);
    }

    final_ln_kernel<<<BN, DMODEL, 0, stream>>>(x_f, gf, bff, out);
}

// Round 7
// 525.585 us; speedup vs baseline: 9.5124x; 1.3617x over previous
//
#include <hip/hip_runtime.h>
#include <hip/hip_bf16.h>
#include <math.h>

// Problem constants (LightGFormer): B=16, N=512, D=256, L=4, H=8, dk=32, Dff=1024
#define BDIM 16
#define NSEQ 512
#define DMODEL 256
#define NLAYER 4
#define NHEAD 8
#define DK 32
#define DFF 1024
#define BN (BDIM * NSEQ)          // 8192 tokens
#define ND (NSEQ * DMODEL)        // 131072

typedef __bf16 bf16x8 __attribute__((ext_vector_type(8)));
typedef float floatx4 __attribute__((ext_vector_type(4)));

// RNE float->bf16 bits
static __device__ __forceinline__ unsigned short f2bf(float f) {
    unsigned u = __float_as_uint(f);
    unsigned r = (u + 0x7FFFu + ((u >> 16) & 1u)) >> 16;
    return (unsigned short)r;
}

// ---------------------------------------------------------------------------
// Weight preconvert: fp32 [L,K,N] -> bf16 [L,N,K] (transposed)
// ---------------------------------------------------------------------------
__global__ void conv_w_kernel(const float* __restrict__ src,
                              unsigned short* __restrict__ dst,
                              int K, int N, int total) {
    int i = blockIdx.x * 256 + threadIdx.x;
    if (i >= total) return;
    int kn = K * N;
    int l = i / kn;
    int rem = i - l * kn;
    int k = rem / N;
    int n = rem - k * N;
    dst[(size_t)l * kn + (size_t)n * K + k] = f2bf(src[i]);
}

// All four 256x256 weight families in one launch (Wq,Wk,Wv,Wo)
__global__ void conv_qkvo_kernel(const float* __restrict__ s0, const float* __restrict__ s1,
                                 const float* __restrict__ s2, const float* __restrict__ s3,
                                 unsigned short* __restrict__ d0, unsigned short* __restrict__ d1,
                                 unsigned short* __restrict__ d2, unsigned short* __restrict__ d3) {
    int i = blockIdx.x * 256 + threadIdx.x;       // 0 .. 4*262144-1
    int sel = i >> 18;                            // 262144 per family
    int j = i & 262143;
    int l = j >> 16;                              // layer
    int rem = j & 65535;
    int k = rem >> 8, n = rem & 255;
    const float* src = sel == 0 ? s0 : sel == 1 ? s1 : sel == 2 ? s2 : s3;
    unsigned short* dst = sel == 0 ? d0 : sel == 1 ? d1 : sel == 2 ? d2 : d3;
    dst[(size_t)l * 65536 + n * 256 + k] = f2bf(src[j]);
}

// mask (int 512x512) -> bitmask (512 x 16 uint32); bit=1 -> -inf
__global__ void conv_mask_kernel(const int* __restrict__ mask,
                                 unsigned* __restrict__ bits) {
    int w = blockIdx.x * blockDim.x + threadIdx.x; // 0..8191
    int r = w >> 4, wi = w & 15;
    const int* src = mask + r * NSEQ + wi * 32;
    unsigned acc = 0;
#pragma unroll
    for (int j = 0; j < 32; j++) acc |= (src[j] != 0 ? 1u : 0u) << j;
    bits[w] = acc;
}

// ---------------------------------------------------------------------------
// x = input + pos (fp32 + bf16) ; xv = input_v + pos (bf16 only)
// ---------------------------------------------------------------------------
__global__ void add_pos_kernel(const float* __restrict__ in,
                               const float* __restrict__ inv,
                               const float* __restrict__ pos,
                               float* __restrict__ x,
                               unsigned short* __restrict__ xb,
                               unsigned short* __restrict__ xvb,
                               int total) {
    int i = blockIdx.x * blockDim.x + threadIdx.x;
    if (i < total) {
        float pe = pos[i % ND];
        float a = in[i] + pe;
        float b = inv[i] + pe;
        x[i] = a;
        xb[i] = f2bf(a);
        xvb[i] = f2bf(b);
    }
}

// ---------------------------------------------------------------------------
// Fused QKV GEMM: grid (6, 64). blockIdx.x: 0,1->Q  2,3->K  4,5->V.
// A = x_b (Q,K) or xv_b (V). Output bf16 head-blocked:
//   [(row/512)*8 + col/32][row%512][col%32]
// ---------------------------------------------------------------------------
__global__ __launch_bounds__(256) void qkv_mfma_kernel(
        const unsigned short* __restrict__ xb,
        const unsigned short* __restrict__ xvb,
        const unsigned short* __restrict__ WqT, const unsigned short* __restrict__ WkT,
        const unsigned short* __restrict__ WvT,
        const float* __restrict__ bq, const float* __restrict__ bk,
        const float* __restrict__ bv,
        unsigned short* __restrict__ qo, unsigned short* __restrict__ ko,
        unsigned short* __restrict__ vo) {
    int proj = blockIdx.x >> 1;
    const unsigned short* A  = (proj == 2) ? xvb : xb;
    const unsigned short* Bt = (proj == 0) ? WqT : (proj == 1) ? WkT : WvT;
    const float* bias        = (proj == 0) ? bq  : (proj == 1) ? bk  : bv;
    unsigned short* Cb       = (proj == 0) ? qo  : (proj == 1) ? ko  : vo;

    __shared__ unsigned short As[128 * 32];
    __shared__ unsigned short Bs[128 * 32];
    int tid = threadIdx.x;
    int wave = tid >> 6, lane = tid & 63;
    int rowBase = blockIdx.y * 128, colBase = (blockIdx.x & 1) * 128;
    int m0w = (wave & 1) * 64, n0w = (wave >> 1) * 64;
    int lr = lane & 15, quad = lane >> 4;

    floatx4 acc[4][4];
#pragma unroll
    for (int mi = 0; mi < 4; mi++)
#pragma unroll
        for (int nj = 0; nj < 4; nj++) acc[mi][nj] = (floatx4)0.0f;

    for (int kt = 0; kt < DMODEL; kt += 32) {
#pragma unroll
        for (int t = 0; t < 2; t++) {
            int idx = tid * 2 + t;
            int row = idx >> 2;
            int kv8 = (idx & 3) * 8;
            *(uint4*)&As[row * 32 + kv8] =
                *(const uint4*)(A + (size_t)(rowBase + row) * DMODEL + kt + kv8);
            *(uint4*)&Bs[row * 32 + kv8] =
                *(const uint4*)(Bt + (size_t)(colBase + row) * DMODEL + kt + kv8);
        }
        __syncthreads();
        bf16x8 af[4], bfr[4];
#pragma unroll
        for (int mi = 0; mi < 4; mi++)
            af[mi] = *(const bf16x8*)&As[(m0w + mi * 16 + lr) * 32 + quad * 8];
#pragma unroll
        for (int nj = 0; nj < 4; nj++)
            bfr[nj] = *(const bf16x8*)&Bs[(n0w + nj * 16 + lr) * 32 + quad * 8];
#pragma unroll
        for (int mi = 0; mi < 4; mi++)
#pragma unroll
            for (int nj = 0; nj < 4; nj++)
                acc[mi][nj] = __builtin_amdgcn_mfma_f32_16x16x32_bf16(
                    af[mi], bfr[nj], acc[mi][nj], 0, 0, 0);
        __syncthreads();
    }

#pragma unroll
    for (int mi = 0; mi < 4; mi++) {
#pragma unroll
        for (int r = 0; r < 4; r++) {
            int grow = rowBase + m0w + mi * 16 + quad * 4 + r;
#pragma unroll
            for (int nj = 0; nj < 4; nj++) {
                int gcol = colBase + n0w + nj * 16 + lr;
                float c = acc[mi][nj][r] + bias[gcol];
                size_t off = ((size_t)((grow >> 9) * 8 + (gcol >> 5)) << 14)
                           + (size_t)(grow & 511) * 32 + (gcol & 31);
                Cb[off] = f2bf(c);
            }
        }
    }
}

// ---------------------------------------------------------------------------
// Generic MFMA GEMM (used for FFN1): C = A @ Bt^T + bias, optional GELU,
// bf16 token-major output. 128x128 tile.
// ---------------------------------------------------------------------------
__global__ __launch_bounds__(256) void gemm_mfma_kernel(
        const unsigned short* __restrict__ A,
        const unsigned short* __restrict__ Bt,
        const float* __restrict__ bias,
        unsigned short* __restrict__ Cb,
        int M, int K, int N, int act) {
    __shared__ unsigned short As[128 * 32];
    __shared__ unsigned short Bs[128 * 32];
    int tid = threadIdx.x;
    int wave = tid >> 6, lane = tid & 63;
    int rowBase = blockIdx.y * 128, colBase = blockIdx.x * 128;
    int m0w = (wave & 1) * 64, n0w = (wave >> 1) * 64;
    int lr = lane & 15, quad = lane >> 4;

    floatx4 acc[4][4];
#pragma unroll
    for (int mi = 0; mi < 4; mi++)
#pragma unroll
        for (int nj = 0; nj < 4; nj++) acc[mi][nj] = (floatx4)0.0f;

    for (int kt = 0; kt < K; kt += 32) {
#pragma unroll
        for (int t = 0; t < 2; t++) {
            int idx = tid * 2 + t;
            int row = idx >> 2;
            int kv8 = (idx & 3) * 8;
            *(uint4*)&As[row * 32 + kv8] =
                *(const uint4*)(A + (size_t)(rowBase + row) * K + kt + kv8);
            *(uint4*)&Bs[row * 32 + kv8] =
                *(const uint4*)(Bt + (size_t)(colBase + row) * K + kt + kv8);
        }
        __syncthreads();
        bf16x8 af[4], bfr[4];
#pragma unroll
        for (int mi = 0; mi < 4; mi++)
            af[mi] = *(const bf16x8*)&As[(m0w + mi * 16 + lr) * 32 + quad * 8];
#pragma unroll
        for (int nj = 0; nj < 4; nj++)
            bfr[nj] = *(const bf16x8*)&Bs[(n0w + nj * 16 + lr) * 32 + quad * 8];
#pragma unroll
        for (int mi = 0; mi < 4; mi++)
#pragma unroll
            for (int nj = 0; nj < 4; nj++)
                acc[mi][nj] = __builtin_amdgcn_mfma_f32_16x16x32_bf16(
                    af[mi], bfr[nj], acc[mi][nj], 0, 0, 0);
        __syncthreads();
    }

#pragma unroll
    for (int mi = 0; mi < 4; mi++) {
#pragma unroll
        for (int r = 0; r < 4; r++) {
            int grow = rowBase + m0w + mi * 16 + quad * 4 + r;
#pragma unroll
            for (int nj = 0; nj < 4; nj++) {
                int gcol = colBase + n0w + nj * 16 + lr;
                float c = acc[mi][nj][r] + bias[gcol];
                if (act) c = 0.5f * c * (1.f + erff(c * 0.70710678118654752f));
                Cb[(size_t)grow * N + gcol] = f2bf(c);
            }
        }
    }
}

// ---------------------------------------------------------------------------
// Fused Wo-GEMM + bias + residual + LayerNorm. Tile 32 rows x 256 cols,
// 128 threads (2 waves, 16 rows each, full row width -> shuffle-only LN).
// In-place update of x_f / x_b.
// ---------------------------------------------------------------------------
__global__ __launch_bounds__(128) void wo_ln_kernel(
        const unsigned short* __restrict__ A,     // ab_b [8192][256]
        const unsigned short* __restrict__ Bt,    // woT [256][256]
        const float* __restrict__ bias,
        const float* __restrict__ g, const float* __restrict__ be,
        float* __restrict__ xf, unsigned short* __restrict__ xb) {
    __shared__ unsigned short As[32 * 32];
    __shared__ unsigned short Bs[256 * 32];
    int tid = threadIdx.x;
    int wave = tid >> 6, lane = tid & 63, l16 = lane & 15, quad = lane >> 4;
    int rowBase = blockIdx.x * 32;

    floatx4 acc[16];
#pragma unroll
    for (int t = 0; t < 16; t++) acc[t] = (floatx4)0.0f;

    for (int kt = 0; kt < 256; kt += 32) {
        {
            int row = tid >> 2, kv8 = (tid & 3) * 8;
            *(uint4*)&As[row * 32 + kv8] =
                *(const uint4*)(A + (size_t)(rowBase + row) * 256 + kt + kv8);
        }
#pragma unroll
        for (int t = 0; t < 8; t++) {
            int idx = t * 128 + tid;
            int row = idx >> 2, kv8 = (idx & 3) * 8;
            *(uint4*)&Bs[row * 32 + kv8] =
                *(const uint4*)(Bt + (size_t)row * 256 + kt + kv8);
        }
        __syncthreads();
        bf16x8 af = *(const bf16x8*)&As[(wave * 16 + l16) * 32 + quad * 8];
#pragma unroll
        for (int t = 0; t < 16; t++) {
            bf16x8 bfr = *(const bf16x8*)&Bs[(t * 16 + l16) * 32 + quad * 8];
            acc[t] = __builtin_amdgcn_mfma_f32_16x16x32_bf16(af, bfr, acc[t], 0, 0, 0);
        }
        __syncthreads();
    }

    float bcol[16], gc[16], bec[16];
#pragma unroll
    for (int t = 0; t < 16; t++) {
        int c = t * 16 + l16;
        bcol[t] = bias[c]; gc[t] = g[c]; bec[t] = be[c];
    }
#pragma unroll
    for (int r = 0; r < 4; r++) {
        int grow = rowBase + wave * 16 + quad * 4 + r;
        float v[16], s = 0.f, s2 = 0.f;
#pragma unroll
        for (int t = 0; t < 16; t++) {
            int c = t * 16 + l16;
            float val = acc[t][r] + bcol[t] + xf[(size_t)grow * 256 + c];
            v[t] = val; s += val; s2 += val * val;
        }
#pragma unroll
        for (int off = 1; off <= 8; off <<= 1) {
            s += __shfl_xor(s, off);
            s2 += __shfl_xor(s2, off);
        }
        float mean = s * (1.f / 256.f);
        float var = s2 * (1.f / 256.f) - mean * mean;
        float rstd = rsqrtf(var + 1e-5f);
#pragma unroll
        for (int t = 0; t < 16; t++) {
            int c = t * 16 + l16;
            float o = (v[t] - mean) * rstd * gc[t] + bec[t];
            xf[(size_t)grow * 256 + c] = o;
            xb[(size_t)grow * 256 + c] = f2bf(o);
        }
    }
}

// ---------------------------------------------------------------------------
// Fused FFN2(grouped) + bias + residual + LayerNorm. M=16384 rows (2/token),
// tile 64 rows x 128 cols = 32 whole tokens. 128 threads (2 waves by col-half).
// Cross-wave LN reduction via small LDS array. In-place x_f / x_b.
// ---------------------------------------------------------------------------
__global__ __launch_bounds__(128) void ffn2_ln_kernel(
        const unsigned short* __restrict__ A,     // h_b [16384][512]
        const unsigned short* __restrict__ Bt,    // w2T [128][512]
        const float* __restrict__ bias,           // [128]
        const float* __restrict__ g, const float* __restrict__ be,
        float* __restrict__ xf, unsigned short* __restrict__ xb) {
    __shared__ unsigned short As[64 * 32];
    __shared__ unsigned short Bs[128 * 32];
    __shared__ float redS[64][2], redQ[64][2];
    int tid = threadIdx.x;
    int wave = tid >> 6, lane = tid & 63, l16 = lane & 15, quad = lane >> 4;
    int rowBase = blockIdx.x * 64;
    int n0w = wave * 64;

    floatx4 acc[4][4];
#pragma unroll
    for (int mi = 0; mi < 4; mi++)
#pragma unroll
        for (int nj = 0; nj < 4; nj++) acc[mi][nj] = (floatx4)0.0f;

    for (int kt = 0; kt < 512; kt += 32) {
#pragma unroll
        for (int t = 0; t < 2; t++) {
            int idx = t * 128 + tid;
            int row = idx >> 2, kv8 = (idx & 3) * 8;
            *(uint4*)&As[row * 32 + kv8] =
                *(const uint4*)(A + (size_t)(rowBase + row) * 512 + kt + kv8);
        }
#pragma unroll
        for (int t = 0; t < 4; t++) {
            int idx = t * 128 + tid;
            int row = idx >> 2, kv8 = (idx & 3) * 8;
            *(uint4*)&Bs[row * 32 + kv8] =
                *(const uint4*)(Bt + (size_t)row * 512 + kt + kv8);
        }
        __syncthreads();
        bf16x8 af[4], bfr[4];
#pragma unroll
        for (int mi = 0; mi < 4; mi++)
            af[mi] = *(const bf16x8*)&As[(mi * 16 + l16) * 32 + quad * 8];
#pragma unroll
        for (int nj = 0; nj < 4; nj++)
            bfr[nj] = *(const bf16x8*)&Bs[(n0w + nj * 16 + l16) * 32 + quad * 8];
#pragma unroll
        for (int mi = 0; mi < 4; mi++)
#pragma unroll
            for (int nj = 0; nj < 4; nj++)
                acc[mi][nj] = __builtin_amdgcn_mfma_f32_16x16x32_bf16(
                    af[mi], bfr[nj], acc[mi][nj], 0, 0, 0);
        __syncthreads();
    }

    // epilogue: v = gemm + bias + residual; per-row partial sums
#pragma unroll
    for (int mi = 0; mi < 4; mi++) {
#pragma unroll
        for (int r = 0; r < 4; r++) {
            int row = mi * 16 + quad * 4 + r;       // 0..63
            int grow = rowBase + row;
            int token = grow >> 1, dbase = (grow & 1) * 128;
            float s = 0.f, s2 = 0.f;
#pragma unroll
            for (int nj = 0; nj < 4; nj++) {
                int gcol = n0w + nj * 16 + l16;
                float val = acc[mi][nj][r] + bias[gcol]
                          + xf[(size_t)token * 256 + dbase + gcol];
                acc[mi][nj][r] = val;
                s += val; s2 += val * val;
            }
#pragma unroll
            for (int off = 1; off <= 8; off <<= 1) {
                s += __shfl_xor(s, off);
                s2 += __shfl_xor(s2, off);
            }
            if (l16 == 0) { redS[row][wave] = s; redQ[row][wave] = s2; }
        }
    }
    __syncthreads();

#pragma unroll
    for (int mi = 0; mi < 4; mi++) {
#pragma unroll
        for (int r = 0; r < 4; r++) {
            int row = mi * 16 + quad * 4 + r;
            int grow = rowBase + row;
            int token = grow >> 1, dbase = (grow & 1) * 128;
            float ts = redS[row][0] + redS[row][1] + redS[row ^ 1][0] + redS[row ^ 1][1];
            float tq = redQ[row][0] + redQ[row][1] + redQ[row ^ 1][0] + redQ[row ^ 1][1];
            float mean = ts * (1.f / 256.f);
            float var = tq * (1.f / 256.f) - mean * mean;
            float rstd = rsqrtf(var + 1e-5f);
#pragma unroll
            for (int nj = 0; nj < 4; nj++) {
                int gcol = n0w + nj * 16 + l16;
                int d = dbase + gcol;
                float o = (acc[mi][nj][r] - mean) * rstd * g[d] + be[d];
                xf[(size_t)token * 256 + d] = o;
                xb[(size_t)token * 256 + d] = f2bf(o);
            }
        }
    }
}

// ---------------------------------------------------------------------------
// MFMA attention (unchanged from R6). Grid = B*H*8 q-groups of 64.
// ---------------------------------------------------------------------------
#define VTS 520
__global__ __launch_bounds__(256) void attn_mfma_kernel(
        const unsigned short* __restrict__ q, const unsigned short* __restrict__ k,
        const unsigned short* __restrict__ v, unsigned short* __restrict__ o,
        const unsigned* __restrict__ mbits_g, int use_mask) {
    int bid = blockIdx.x;
    int qg = bid & 7, h = (bid >> 3) & 7, b = bid >> 6;
    int tid = threadIdx.x;

    __shared__ unsigned short Ks[NSEQ * DK];
    __shared__ unsigned short Vt[DK * VTS];

    const unsigned short* kbase = k + (size_t)(b * 8 + h) * (NSEQ * DK);
    const unsigned short* vbase = v + (size_t)(b * 8 + h) * (NSEQ * DK);

    for (int c = tid; c < NSEQ * DK / 8; c += 256)
        ((uint4*)Ks)[c] = ((const uint4*)kbase)[c];
#pragma unroll
    for (int r = 0; r < 2; r++) {
        int kk = tid + r * 256;
        unsigned short tmp[32];
        *(uint4*)&tmp[0]  = *(const uint4*)(vbase + (size_t)kk * 32);
        *(uint4*)&tmp[8]  = *(const uint4*)(vbase + (size_t)kk * 32 + 8);
        *(uint4*)&tmp[16] = *(const uint4*)(vbase + (size_t)kk * 32 + 16);
        *(uint4*)&tmp[24] = *(const uint4*)(vbase + (size_t)kk * 32 + 24);
#pragma unroll
        for (int d = 0; d < 32; d++) Vt[d * VTS + kk] = tmp[d];
    }

    int wave = tid >> 6, lane = tid & 63, l16 = lane & 15, quad = lane >> 4;
    int qbase = qg * 64 + wave * 16;

    bf16x8 qf = *(const bf16x8*)(q + ((size_t)(b * 8 + h) * NSEQ + qbase + l16) * 32 + quad * 8);

    unsigned mw[16];
    if (use_mask) {
        const uint4* mr = (const uint4*)(mbits_g + (size_t)(qbase + l16) * 16);
#pragma unroll
        for (int w = 0; w < 4; w++) *(uint4*)&mw[w * 4] = mr[w];
    } else {
#pragma unroll
        for (int w = 0; w < 16; w++) mw[w] = 0;
    }
    __syncthreads();

    floatx4 oT0 = (floatx4)0.f, oT1 = (floatx4)0.f;
    float m_run = -INFINITY, l_part = 0.f;
    const float scale = 0.17677669529663687f;

#pragma unroll
    for (int c = 0; c < 16; c++) {
        int kkb = c * 32;
        bf16x8 k0 = *(const bf16x8*)&Ks[(kkb + l16) * 32 + quad * 8];
        bf16x8 k1 = *(const bf16x8*)&Ks[(kkb + 16 + l16) * 32 + quad * 8];
        floatx4 s0 = __builtin_amdgcn_mfma_f32_16x16x32_bf16(k0, qf, (floatx4)0.f, 0, 0, 0);
        floatx4 s1 = __builtin_amdgcn_mfma_f32_16x16x32_bf16(k1, qf, (floatx4)0.f, 0, 0, 0);

        float sv[8];
#pragma unroll
        for (int r = 0; r < 4; r++) { sv[r] = s0[r] * scale; sv[4 + r] = s1[r] * scale; }
        if (use_mask) {
            unsigned wb = mw[c];
#pragma unroll
            for (int r = 0; r < 4; r++) {
                if ((wb >> (quad * 4 + r)) & 1) sv[r] = -INFINITY;
                if ((wb >> (16 + quad * 4 + r)) & 1) sv[4 + r] = -INFINITY;
            }
        }
        float mx = sv[0];
#pragma unroll
        for (int j = 1; j < 8; j++) mx = fmaxf(mx, sv[j]);
        mx = fmaxf(mx, __shfl_xor(mx, 16));
        mx = fmaxf(mx, __shfl_xor(mx, 32));
        float mnew = fmaxf(m_run, mx);
        float corr = (m_run == mnew) ? 1.f : __expf(m_run - mnew);
        l_part *= corr;
        oT0 *= corr; oT1 *= corr;
        float p[8];
#pragma unroll
        for (int j = 0; j < 8; j++) {
            float e = __expf(sv[j] - mnew);
            p[j] = (sv[j] > -INFINITY) ? e : 0.f;
            l_part += p[j];
        }
        union { bf16x8 v; unsigned short u[8]; } pf;
#pragma unroll
        for (int j = 0; j < 8; j++) pf.u[j] = f2bf(p[j]);

        bf16x8 av0, av1;
        ((uint2*)&av0)[0] = *(const uint2*)&Vt[l16 * VTS + kkb + quad * 4];
        ((uint2*)&av0)[1] = *(const uint2*)&Vt[l16 * VTS + kkb + 16 + quad * 4];
        ((uint2*)&av1)[0] = *(const uint2*)&Vt[(16 + l16) * VTS + kkb + quad * 4];
        ((uint2*)&av1)[1] = *(const uint2*)&Vt[(16 + l16) * VTS + kkb + 16 + quad * 4];

        oT0 = __builtin_amdgcn_mfma_f32_16x16x32_bf16(av0, pf.v, oT0, 0, 0, 0);
        oT1 = __builtin_amdgcn_mfma_f32_16x16x32_bf16(av1, pf.v, oT1, 0, 0, 0);
        m_run = mnew;
    }

    float l = l_part;
    l += __shfl_xor(l, 16);
    l += __shfl_xor(l, 32);
    float invl = (l > 0.f) ? 1.f / l : 0.f;

    unsigned short* orow = o + ((size_t)(b * NSEQ + qbase + l16)) * DMODEL + h * DK;
#pragma unroll
    for (int r = 0; r < 4; r++) {
        orow[quad * 4 + r]      = f2bf(oT0[r] * invl);
        orow[16 + quad * 4 + r] = f2bf(oT1[r] * invl);
    }
}

// Final LN: out = LayerNorm(x) * gf + bf (fp32)
__global__ __launch_bounds__(256) void final_ln_kernel(
        const float* __restrict__ a,
        const float* __restrict__ g, const float* __restrict__ be,
        float* __restrict__ out) {
    int t = blockIdx.x;
    int d = threadIdx.x;
    size_t idx = (size_t)t * DMODEL + d;
    float v = a[idx];
    float s = v, s2 = v * v;
#pragma unroll
    for (int off = 32; off; off >>= 1) {
        s  += __shfl_xor(s, off);
        s2 += __shfl_xor(s2, off);
    }
    __shared__ float ws1[4], ws2[4];
    int wid = d >> 6;
    if ((d & 63) == 0) { ws1[wid] = s; ws2[wid] = s2; }
    __syncthreads();
    s  = ws1[0] + ws1[1] + ws1[2] + ws1[3];
    s2 = ws2[0] + ws2[1] + ws2[2] + ws2[3];
    float mean = s * (1.f / DMODEL);
    float var = s2 * (1.f / DMODEL) - mean * mean;
    float rstd = rsqrtf(var + 1e-5f);
    out[idx] = (v - mean) * rstd * g[d] + be[d];
}

// ---------------------------------------------------------------------------
extern "C" void kernel_launch(void* const* d_in, const int* in_sizes, int n_in,
                              void* d_out, int out_size, void* d_ws, size_t ws_size,
                              hipStream_t stream) {
    const float* input  = (const float*)d_in[0];
    const float* inputv = (const float*)d_in[1];
    const float* pos    = (const float*)d_in[2];
    const float* Wq = (const float*)d_in[3];
    const float* bq = (const float*)d_in[4];
    const float* Wk = (const float*)d_in[5];
    const float* bk = (const float*)d_in[6];
    const float* Wv = (const float*)d_in[7];
    const float* bv = (const float*)d_in[8];
    const float* Wo = (const float*)d_in[9];
    const float* bo = (const float*)d_in[10];
    const float* W1 = (const float*)d_in[11];
    const float* b1 = (const float*)d_in[12];
    const float* W2 = (const float*)d_in[13];
    const float* b2 = (const float*)d_in[14];
    const float* g1 = (const float*)d_in[15];
    const float* be1 = (const float*)d_in[16];
    const float* g2 = (const float*)d_in[17];
    const float* be2 = (const float*)d_in[18];
    const float* gf = (const float*)d_in[19];
    const float* bff = (const float*)d_in[20];
    const int* mask = (const int*)d_in[21];

    float* out = (float*)d_out;

    // Workspace layout (bytes), ~37 MB
    char* wsb = (char*)d_ws;
    float* x_f  = (float*)(wsb + ((size_t)0 << 20));                    // 8 MB
    unsigned short* x_b  = (unsigned short*)(wsb + ((size_t)8 << 20));  // 4 MB
    unsigned short* xv_b = (unsigned short*)(wsb + ((size_t)12 << 20)); // 4 MB
    unsigned short* qb_b = (unsigned short*)(wsb + ((size_t)16 << 20)); // 4 MB
    unsigned short* kb_b = (unsigned short*)(wsb + ((size_t)20 << 20)); // 4 MB
    unsigned short* vb_b = (unsigned short*)(wsb + ((size_t)24 << 20)); // 4 MB
    unsigned short* ab_b = (unsigned short*)(wsb + ((size_t)28 << 20)); // 4 MB
    unsigned short* h_b  = qb_b;  // 16 MB alias over qb..ab (dead during FFN)
    unsigned short* wqT = (unsigned short*)(wsb + ((size_t)32 << 20));
    unsigned short* wkT = wqT + (size_t)4 * 65536;
    unsigned short* wvT = wkT + (size_t)4 * 65536;
    unsigned short* woT = wvT + (size_t)4 * 65536;
    unsigned short* w1T = woT + (size_t)4 * 65536;   // 4 x 262144
    unsigned short* w2T = w1T + (size_t)4 * 262144;  // 4 x 65536
    unsigned* mbits = (unsigned*)(wsb + ((size_t)37 << 20));            // 32 KB

    const size_t TOK = (size_t)BN * DMODEL;

    // --- preconversions (5 dispatches) ---
    conv_qkvo_kernel<<<4096, 256, 0, stream>>>(Wq, Wk, Wv, Wo, wqT, wkT, wvT, woT);
    int tw1 = 4 * 256 * 1024;
    conv_w_kernel<<<(tw1 + 255) / 256, 256, 0, stream>>>(W1, w1T, 256, 1024, tw1);
    int tw2 = 4 * 512 * 128;
    conv_w_kernel<<<(tw2 + 255) / 256, 256, 0, stream>>>(W2, w2T, 512, 128, tw2);
    conv_mask_kernel<<<8192 / 256, 256, 0, stream>>>(mask, mbits);
    add_pos_kernel<<<(int)((TOK + 255) / 256), 256, 0, stream>>>(
        input, inputv, pos, x_f, x_b, xv_b, (int)TOK);

    for (int i = 0; i < NLAYER; i++) {
        const unsigned short* WqT_i = wqT + (size_t)i * 65536;
        const unsigned short* WkT_i = wkT + (size_t)i * 65536;
        const unsigned short* WvT_i = wvT + (size_t)i * 65536;
        const unsigned short* WoT_i = woT + (size_t)i * 65536;
        const unsigned short* W1T_i = w1T + (size_t)i * 262144;
        const unsigned short* W2T_i = w2T + (size_t)i * 65536;

        qkv_mfma_kernel<<<dim3(6, 64), 256, 0, stream>>>(
            x_b, xv_b, WqT_i, WkT_i, WvT_i,
            bq + i * DMODEL, bk + i * DMODEL, bv + i * DMODEL,
            qb_b, kb_b, vb_b);

        attn_mfma_kernel<<<BDIM * NHEAD * 8, 256, 0, stream>>>(
            qb_b, kb_b, vb_b, ab_b, mbits, (i & 1));

        wo_ln_kernel<<<BN / 32, 128, 0, stream>>>(
            ab_b, WoT_i, bo + i * DMODEL,
            g1 + i * DMODEL, be1 + i * DMODEL, x_f, x_b);

        gemm_mfma_kernel<<<dim3(8, 64), 256, 0, stream>>>(
            x_b, W1T_i, b1 + i * DFF, h_b, BN, DMODEL, DFF, 1);

        ffn2_ln_kernel<<<(2 * BN) / 64, 128, 0, stream>>>(
            h_b, W2T_i, b2 + i * (DMODEL / 2),
            g2 + i * DMODEL, be2 + i * DMODEL, x_f, x_b);
    }

    final_ln_kernel<<<BN, DMODEL, 0, stream>>>(x_f, gf, bff, out);
}

// Round 8
// 499.443 us; speedup vs baseline: 10.0103x; 1.0523x over previous
//
#include <hip/hip_runtime.h>
#include <hip/hip_bf16.h>
#include <math.h>

// Problem constants (LightGFormer): B=16, N=512, D=256, L=4, H=8, dk=32, Dff=1024
#define BDIM 16
#define NSEQ 512
#define DMODEL 256
#define NLAYER 4
#define NHEAD 8
#define DK 32
#define DFF 1024
#define BN (BDIM * NSEQ)          // 8192 tokens
#define ND (NSEQ * DMODEL)        // 131072

typedef __bf16 bf16x8 __attribute__((ext_vector_type(8)));
typedef float floatx4 __attribute__((ext_vector_type(4)));

// RNE float->bf16 bits
static __device__ __forceinline__ unsigned short f2bf(float f) {
    unsigned u = __float_as_uint(f);
    unsigned r = (u + 0x7FFFu + ((u >> 16) & 1u)) >> 16;
    return (unsigned short)r;
}

// async 16-byte global->LDS copy (wave-uniform LDS base + lane*16 required)
static __device__ __forceinline__ void async_ld16(const unsigned short* g,
                                                  unsigned short* l) {
    __builtin_amdgcn_global_load_lds(
        (const __attribute__((address_space(1))) unsigned int*)g,
        (__attribute__((address_space(3))) unsigned int*)l, 16, 0, 0);
}

// sigmoid-form tanh-approx GELU, |err| < 1e-3 vs exact
static __device__ __forceinline__ float gelu_f(float c) {
    float u = 0.7978845608028654f * (c + 0.044715f * c * c * c);
    return c * (1.f / (1.f + __expf(-2.f * u)));
}

// ---------------------------------------------------------------------------
// All four 256x256 weight families in one launch (Wq,Wk,Wv,Wo): [L,K,N]->[L,N,K]
// ---------------------------------------------------------------------------
__global__ void conv_qkvo_kernel(const float* __restrict__ s0, const float* __restrict__ s1,
                                 const float* __restrict__ s2, const float* __restrict__ s3,
                                 unsigned short* __restrict__ d0, unsigned short* __restrict__ d1,
                                 unsigned short* __restrict__ d2, unsigned short* __restrict__ d3) {
    int i = blockIdx.x * 256 + threadIdx.x;       // 0 .. 4*262144-1
    int sel = i >> 18;
    int j = i & 262143;
    int l = j >> 16;
    int rem = j & 65535;
    int k = rem >> 8, n = rem & 255;
    const float* src = sel == 0 ? s0 : sel == 1 ? s1 : sel == 2 ? s2 : s3;
    unsigned short* dst = sel == 0 ? d0 : sel == 1 ? d1 : sel == 2 ? d2 : d3;
    dst[(size_t)l * 65536 + n * 256 + k] = f2bf(src[j]);
}

// W1 [4,256,1024] and W2 [4,512,128] transposed-bf16 in one launch
__global__ void conv_w12_kernel(const float* __restrict__ W1, const float* __restrict__ W2,
                                unsigned short* __restrict__ w1T, unsigned short* __restrict__ w2T) {
    int i = blockIdx.x * 256 + threadIdx.x;
    if (i < 4 * 262144) {
        int l = i >> 18, rem = i & 262143, k = rem >> 10, n = rem & 1023;
        w1T[(size_t)l * 262144 + (size_t)n * 256 + k] = f2bf(W1[i]);
    } else {
        int j = i - 4 * 262144;
        if (j < 4 * 65536) {
            int l = j >> 16, rem = j & 65535, k = rem >> 7, n = rem & 127;
            w2T[(size_t)l * 65536 + (size_t)n * 512 + k] = f2bf(W2[j]);
        }
    }
}

// mask (int 512x512) -> bitmask (512 x 16 uint32); bit=1 -> -inf
__global__ void conv_mask_kernel(const int* __restrict__ mask,
                                 unsigned* __restrict__ bits) {
    int w = blockIdx.x * blockDim.x + threadIdx.x; // 0..8191
    int r = w >> 4, wi = w & 15;
    const int* src = mask + r * NSEQ + wi * 32;
    unsigned acc = 0;
#pragma unroll
    for (int j = 0; j < 32; j++) acc |= (src[j] != 0 ? 1u : 0u) << j;
    bits[w] = acc;
}

// ---------------------------------------------------------------------------
// x = input + pos (fp32 + bf16) ; xv = input_v + pos (bf16 only)
// ---------------------------------------------------------------------------
__global__ void add_pos_kernel(const float* __restrict__ in,
                               const float* __restrict__ inv,
                               const float* __restrict__ pos,
                               float* __restrict__ x,
                               unsigned short* __restrict__ xb,
                               unsigned short* __restrict__ xvb,
                               int total) {
    int i = blockIdx.x * blockDim.x + threadIdx.x;
    if (i < total) {
        float pe = pos[i % ND];
        float a = in[i] + pe;
        float b = inv[i] + pe;
        x[i] = a;
        xb[i] = f2bf(a);
        xvb[i] = f2bf(b);
    }
}

// ---------------------------------------------------------------------------
// Fused QKV GEMM: grid (6, 64). blockIdx.x: 0,1->Q  2,3->K  4,5->V.
// Output bf16 head-blocked: [(row/512)*8 + col/32][row%512][col%32]
// ---------------------------------------------------------------------------
__global__ __launch_bounds__(256) void qkv_mfma_kernel(
        const unsigned short* __restrict__ xb,
        const unsigned short* __restrict__ xvb,
        const unsigned short* __restrict__ WqT, const unsigned short* __restrict__ WkT,
        const unsigned short* __restrict__ WvT,
        const float* __restrict__ bq, const float* __restrict__ bk,
        const float* __restrict__ bv,
        unsigned short* __restrict__ qo, unsigned short* __restrict__ ko,
        unsigned short* __restrict__ vo) {
    int proj = blockIdx.x >> 1;
    const unsigned short* A  = (proj == 2) ? xvb : xb;
    const unsigned short* Bt = (proj == 0) ? WqT : (proj == 1) ? WkT : WvT;
    const float* bias        = (proj == 0) ? bq  : (proj == 1) ? bk  : bv;
    unsigned short* Cb       = (proj == 0) ? qo  : (proj == 1) ? ko  : vo;

    __shared__ unsigned short As[128 * 32];
    __shared__ unsigned short Bs[128 * 32];
    int tid = threadIdx.x;
    int wave = tid >> 6, lane = tid & 63;
    int rowBase = blockIdx.y * 128, colBase = (blockIdx.x & 1) * 128;
    int m0w = (wave & 1) * 64, n0w = (wave >> 1) * 64;
    int lr = lane & 15, quad = lane >> 4;

    floatx4 acc[4][4];
#pragma unroll
    for (int mi = 0; mi < 4; mi++)
#pragma unroll
        for (int nj = 0; nj < 4; nj++) acc[mi][nj] = (floatx4)0.0f;

    for (int kt = 0; kt < DMODEL; kt += 32) {
#pragma unroll
        for (int t = 0; t < 2; t++) {
            int idx = t * 256 + tid;
            int row = idx >> 2, kv8 = (idx & 3) * 8;
            async_ld16(A + (size_t)(rowBase + row) * DMODEL + kt + kv8, &As[idx * 8]);
            async_ld16(Bt + (size_t)(colBase + row) * DMODEL + kt + kv8, &Bs[idx * 8]);
        }
        __syncthreads();
        bf16x8 af[4], bfr[4];
#pragma unroll
        for (int mi = 0; mi < 4; mi++)
            af[mi] = *(const bf16x8*)&As[(m0w + mi * 16 + lr) * 32 + quad * 8];
#pragma unroll
        for (int nj = 0; nj < 4; nj++)
            bfr[nj] = *(const bf16x8*)&Bs[(n0w + nj * 16 + lr) * 32 + quad * 8];
#pragma unroll
        for (int mi = 0; mi < 4; mi++)
#pragma unroll
            for (int nj = 0; nj < 4; nj++)
                acc[mi][nj] = __builtin_amdgcn_mfma_f32_16x16x32_bf16(
                    af[mi], bfr[nj], acc[mi][nj], 0, 0, 0);
        __syncthreads();
    }

#pragma unroll
    for (int mi = 0; mi < 4; mi++) {
#pragma unroll
        for (int r = 0; r < 4; r++) {
            int grow = rowBase + m0w + mi * 16 + quad * 4 + r;
#pragma unroll
            for (int nj = 0; nj < 4; nj++) {
                int gcol = colBase + n0w + nj * 16 + lr;
                float c = acc[mi][nj][r] + bias[gcol];
                size_t off = ((size_t)((grow >> 9) * 8 + (gcol >> 5)) << 14)
                           + (size_t)(grow & 511) * 32 + (gcol & 31);
                Cb[off] = f2bf(c);
            }
        }
    }
}

// ---------------------------------------------------------------------------
// Generic MFMA GEMM (FFN1): C = A @ Bt^T + bias, optional GELU, bf16 out.
// ---------------------------------------------------------------------------
__global__ __launch_bounds__(256) void gemm_mfma_kernel(
        const unsigned short* __restrict__ A,
        const unsigned short* __restrict__ Bt,
        const float* __restrict__ bias,
        unsigned short* __restrict__ Cb,
        int M, int K, int N, int act) {
    __shared__ unsigned short As[128 * 32];
    __shared__ unsigned short Bs[128 * 32];
    int tid = threadIdx.x;
    int wave = tid >> 6, lane = tid & 63;
    int rowBase = blockIdx.y * 128, colBase = blockIdx.x * 128;
    int m0w = (wave & 1) * 64, n0w = (wave >> 1) * 64;
    int lr = lane & 15, quad = lane >> 4;

    floatx4 acc[4][4];
#pragma unroll
    for (int mi = 0; mi < 4; mi++)
#pragma unroll
        for (int nj = 0; nj < 4; nj++) acc[mi][nj] = (floatx4)0.0f;

    for (int kt = 0; kt < K; kt += 32) {
#pragma unroll
        for (int t = 0; t < 2; t++) {
            int idx = t * 256 + tid;
            int row = idx >> 2, kv8 = (idx & 3) * 8;
            async_ld16(A + (size_t)(rowBase + row) * K + kt + kv8, &As[idx * 8]);
            async_ld16(Bt + (size_t)(colBase + row) * K + kt + kv8, &Bs[idx * 8]);
        }
        __syncthreads();
        bf16x8 af[4], bfr[4];
#pragma unroll
        for (int mi = 0; mi < 4; mi++)
            af[mi] = *(const bf16x8*)&As[(m0w + mi * 16 + lr) * 32 + quad * 8];
#pragma unroll
        for (int nj = 0; nj < 4; nj++)
            bfr[nj] = *(const bf16x8*)&Bs[(n0w + nj * 16 + lr) * 32 + quad * 8];
#pragma unroll
        for (int mi = 0; mi < 4; mi++)
#pragma unroll
            for (int nj = 0; nj < 4; nj++)
                acc[mi][nj] = __builtin_amdgcn_mfma_f32_16x16x32_bf16(
                    af[mi], bfr[nj], acc[mi][nj], 0, 0, 0);
        __syncthreads();
    }

#pragma unroll
    for (int mi = 0; mi < 4; mi++) {
#pragma unroll
        for (int r = 0; r < 4; r++) {
            int grow = rowBase + m0w + mi * 16 + quad * 4 + r;
#pragma unroll
            for (int nj = 0; nj < 4; nj++) {
                int gcol = colBase + n0w + nj * 16 + lr;
                float c = acc[mi][nj][r] + bias[gcol];
                if (act) c = gelu_f(c);
                Cb[(size_t)grow * N + gcol] = f2bf(c);
            }
        }
    }
}

// ---------------------------------------------------------------------------
// Fused Wo-GEMM + bias + residual + LayerNorm. 32 rows x 256 cols, 128 thr.
// ---------------------------------------------------------------------------
__global__ __launch_bounds__(128) void wo_ln_kernel(
        const unsigned short* __restrict__ A,     // ab_b [8192][256]
        const unsigned short* __restrict__ Bt,    // woT [256][256]
        const float* __restrict__ bias,
        const float* __restrict__ g, const float* __restrict__ be,
        float* __restrict__ xf, unsigned short* __restrict__ xb) {
    __shared__ unsigned short As[32 * 32];
    __shared__ unsigned short Bs[256 * 32];
    int tid = threadIdx.x;
    int wave = tid >> 6, lane = tid & 63, l16 = lane & 15, quad = lane >> 4;
    int rowBase = blockIdx.x * 32;

    floatx4 acc[16];
#pragma unroll
    for (int t = 0; t < 16; t++) acc[t] = (floatx4)0.0f;

    for (int kt = 0; kt < 256; kt += 32) {
        {
            int row = tid >> 2, kv8 = (tid & 3) * 8;
            async_ld16(A + (size_t)(rowBase + row) * 256 + kt + kv8, &As[tid * 8]);
        }
#pragma unroll
        for (int t = 0; t < 8; t++) {
            int idx = t * 128 + tid;
            int row = idx >> 2, kv8 = (idx & 3) * 8;
            async_ld16(Bt + (size_t)row * 256 + kt + kv8, &Bs[idx * 8]);
        }
        __syncthreads();
        bf16x8 af = *(const bf16x8*)&As[(wave * 16 + l16) * 32 + quad * 8];
#pragma unroll
        for (int t = 0; t < 16; t++) {
            bf16x8 bfr = *(const bf16x8*)&Bs[(t * 16 + l16) * 32 + quad * 8];
            acc[t] = __builtin_amdgcn_mfma_f32_16x16x32_bf16(af, bfr, acc[t], 0, 0, 0);
        }
        __syncthreads();
    }

    float bcol[16], gc[16], bec[16];
#pragma unroll
    for (int t = 0; t < 16; t++) {
        int c = t * 16 + l16;
        bcol[t] = bias[c]; gc[t] = g[c]; bec[t] = be[c];
    }
#pragma unroll
    for (int r = 0; r < 4; r++) {
        int grow = rowBase + wave * 16 + quad * 4 + r;
        float v[16], s = 0.f, s2 = 0.f;
#pragma unroll
        for (int t = 0; t < 16; t++) {
            int c = t * 16 + l16;
            float val = acc[t][r] + bcol[t] + xf[(size_t)grow * 256 + c];
            v[t] = val; s += val; s2 += val * val;
        }
#pragma unroll
        for (int off = 1; off <= 8; off <<= 1) {
            s += __shfl_xor(s, off);
            s2 += __shfl_xor(s2, off);
        }
        float mean = s * (1.f / 256.f);
        float var = s2 * (1.f / 256.f) - mean * mean;
        float rstd = rsqrtf(var + 1e-5f);
#pragma unroll
        for (int t = 0; t < 16; t++) {
            int c = t * 16 + l16;
            float o = (v[t] - mean) * rstd * gc[t] + bec[t];
            xf[(size_t)grow * 256 + c] = o;
            xb[(size_t)grow * 256 + c] = f2bf(o);
        }
    }
}

// ---------------------------------------------------------------------------
// Fused FFN2(grouped) + bias + residual + LayerNorm. 64 rows x 128 cols.
// ---------------------------------------------------------------------------
__global__ __launch_bounds__(128) void ffn2_ln_kernel(
        const unsigned short* __restrict__ A,     // h_b [16384][512]
        const unsigned short* __restrict__ Bt,    // w2T [128][512]
        const float* __restrict__ bias,           // [128]
        const float* __restrict__ g, const float* __restrict__ be,
        float* __restrict__ xf, unsigned short* __restrict__ xb) {
    __shared__ unsigned short As[64 * 32];
    __shared__ unsigned short Bs[128 * 32];
    __shared__ float redS[64][2], redQ[64][2];
    int tid = threadIdx.x;
    int wave = tid >> 6, lane = tid & 63, l16 = lane & 15, quad = lane >> 4;
    int rowBase = blockIdx.x * 64;
    int n0w = wave * 64;

    floatx4 acc[4][4];
#pragma unroll
    for (int mi = 0; mi < 4; mi++)
#pragma unroll
        for (int nj = 0; nj < 4; nj++) acc[mi][nj] = (floatx4)0.0f;

    for (int kt = 0; kt < 512; kt += 32) {
#pragma unroll
        for (int t = 0; t < 2; t++) {
            int idx = t * 128 + tid;
            int row = idx >> 2, kv8 = (idx & 3) * 8;
            async_ld16(A + (size_t)(rowBase + row) * 512 + kt + kv8, &As[idx * 8]);
        }
#pragma unroll
        for (int t = 0; t < 4; t++) {
            int idx = t * 128 + tid;
            int row = idx >> 2, kv8 = (idx & 3) * 8;
            async_ld16(Bt + (size_t)row * 512 + kt + kv8, &Bs[idx * 8]);
        }
        __syncthreads();
        bf16x8 af[4], bfr[4];
#pragma unroll
        for (int mi = 0; mi < 4; mi++)
            af[mi] = *(const bf16x8*)&As[(mi * 16 + l16) * 32 + quad * 8];
#pragma unroll
        for (int nj = 0; nj < 4; nj++)
            bfr[nj] = *(const bf16x8*)&Bs[(n0w + nj * 16 + l16) * 32 + quad * 8];
#pragma unroll
        for (int mi = 0; mi < 4; mi++)
#pragma unroll
            for (int nj = 0; nj < 4; nj++)
                acc[mi][nj] = __builtin_amdgcn_mfma_f32_16x16x32_bf16(
                    af[mi], bfr[nj], acc[mi][nj], 0, 0, 0);
        __syncthreads();
    }

#pragma unroll
    for (int mi = 0; mi < 4; mi++) {
#pragma unroll
        for (int r = 0; r < 4; r++) {
            int row = mi * 16 + quad * 4 + r;       // 0..63
            int grow = rowBase + row;
            int token = grow >> 1, dbase = (grow & 1) * 128;
            float s = 0.f, s2 = 0.f;
#pragma unroll
            for (int nj = 0; nj < 4; nj++) {
                int gcol = n0w + nj * 16 + l16;
                float val = acc[mi][nj][r] + bias[gcol]
                          + xf[(size_t)token * 256 + dbase + gcol];
                acc[mi][nj][r] = val;
                s += val; s2 += val * val;
            }
#pragma unroll
            for (int off = 1; off <= 8; off <<= 1) {
                s += __shfl_xor(s, off);
                s2 += __shfl_xor(s2, off);
            }
            if (l16 == 0) { redS[row][wave] = s; redQ[row][wave] = s2; }
        }
    }
    __syncthreads();

#pragma unroll
    for (int mi = 0; mi < 4; mi++) {
#pragma unroll
        for (int r = 0; r < 4; r++) {
            int row = mi * 16 + quad * 4 + r;
            int grow = rowBase + row;
            int token = grow >> 1, dbase = (grow & 1) * 128;
            float ts = redS[row][0] + redS[row][1] + redS[row ^ 1][0] + redS[row ^ 1][1];
            float tq = redQ[row][0] + redQ[row][1] + redQ[row ^ 1][0] + redQ[row ^ 1][1];
            float mean = ts * (1.f / 256.f);
            float var = tq * (1.f / 256.f) - mean * mean;
            float rstd = rsqrtf(var + 1e-5f);
#pragma unroll
            for (int nj = 0; nj < 4; nj++) {
                int gcol = n0w + nj * 16 + l16;
                int d = dbase + gcol;
                float o = (acc[mi][nj][r] - mean) * rstd * g[d] + be[d];
                xf[(size_t)token * 256 + d] = o;
                xb[(size_t)token * 256 + d] = f2bf(o);
            }
        }
    }
}

// ---------------------------------------------------------------------------
// MFMA attention. Grid = B*H*8 q-groups of 64.
// ---------------------------------------------------------------------------
#define VTS 520
__global__ __launch_bounds__(256) void attn_mfma_kernel(
        const unsigned short* __restrict__ q, const unsigned short* __restrict__ k,
        const unsigned short* __restrict__ v, unsigned short* __restrict__ o,
        const unsigned* __restrict__ mbits_g, int use_mask) {
    int bid = blockIdx.x;
    int qg = bid & 7, h = (bid >> 3) & 7, b = bid >> 6;
    int tid = threadIdx.x;

    __shared__ unsigned short Ks[NSEQ * DK];
    __shared__ unsigned short Vt[DK * VTS];

    const unsigned short* kbase = k + (size_t)(b * 8 + h) * (NSEQ * DK);
    const unsigned short* vbase = v + (size_t)(b * 8 + h) * (NSEQ * DK);

#pragma unroll
    for (int t = 0; t < 8; t++) {
        int idx = t * 256 + tid;
        async_ld16(kbase + (size_t)idx * 8, &Ks[idx * 8]);
    }
#pragma unroll
    for (int r = 0; r < 2; r++) {
        int kk = tid + r * 256;
        unsigned short tmp[32];
        *(uint4*)&tmp[0]  = *(const uint4*)(vbase + (size_t)kk * 32);
        *(uint4*)&tmp[8]  = *(const uint4*)(vbase + (size_t)kk * 32 + 8);
        *(uint4*)&tmp[16] = *(const uint4*)(vbase + (size_t)kk * 32 + 16);
        *(uint4*)&tmp[24] = *(const uint4*)(vbase + (size_t)kk * 32 + 24);
#pragma unroll
        for (int d = 0; d < 32; d++) Vt[d * VTS + kk] = tmp[d];
    }

    int wave = tid >> 6, lane = tid & 63, l16 = lane & 15, quad = lane >> 4;
    int qbase = qg * 64 + wave * 16;

    bf16x8 qf = *(const bf16x8*)(q + ((size_t)(b * 8 + h) * NSEQ + qbase + l16) * 32 + quad * 8);

    unsigned mw[16];
    if (use_mask) {
        const uint4* mr = (const uint4*)(mbits_g + (size_t)(qbase + l16) * 16);
#pragma unroll
        for (int w = 0; w < 4; w++) *(uint4*)&mw[w * 4] = mr[w];
    } else {
#pragma unroll
        for (int w = 0; w < 16; w++) mw[w] = 0;
    }
    __syncthreads();

    floatx4 oT0 = (floatx4)0.f, oT1 = (floatx4)0.f;
    float m_run = -INFINITY, l_part = 0.f;
    const float scale = 0.17677669529663687f;

#pragma unroll
    for (int c = 0; c < 16; c++) {
        int kkb = c * 32;
        bf16x8 k0 = *(const bf16x8*)&Ks[(kkb + l16) * 32 + quad * 8];
        bf16x8 k1 = *(const bf16x8*)&Ks[(kkb + 16 + l16) * 32 + quad * 8];
        floatx4 s0 = __builtin_amdgcn_mfma_f32_16x16x32_bf16(k0, qf, (floatx4)0.f, 0, 0, 0);
        floatx4 s1 = __builtin_amdgcn_mfma_f32_16x16x32_bf16(k1, qf, (floatx4)0.f, 0, 0, 0);

        float sv[8];
#pragma unroll
        for (int r = 0; r < 4; r++) { sv[r] = s0[r] * scale; sv[4 + r] = s1[r] * scale; }
        if (use_mask) {
            unsigned wb = mw[c];
#pragma unroll
            for (int r = 0; r < 4; r++) {
                if ((wb >> (quad * 4 + r)) & 1) sv[r] = -INFINITY;
                if ((wb >> (16 + quad * 4 + r)) & 1) sv[4 + r] = -INFINITY;
            }
        }
        float mx = sv[0];
#pragma unroll
        for (int j = 1; j < 8; j++) mx = fmaxf(mx, sv[j]);
        mx = fmaxf(mx, __shfl_xor(mx, 16));
        mx = fmaxf(mx, __shfl_xor(mx, 32));
        float mnew = fmaxf(m_run, mx);
        float corr = (m_run == mnew) ? 1.f : __expf(m_run - mnew);
        l_part *= corr;
        oT0 *= corr; oT1 *= corr;
        float p[8];
#pragma unroll
        for (int j = 0; j < 8; j++) {
            float e = __expf(sv[j] - mnew);
            p[j] = (sv[j] > -INFINITY) ? e : 0.f;
            l_part += p[j];
        }
        union { bf16x8 v; unsigned short u[8]; } pf;
#pragma unroll
        for (int j = 0; j < 8; j++) pf.u[j] = f2bf(p[j]);

        bf16x8 av0, av1;
        ((uint2*)&av0)[0] = *(const uint2*)&Vt[l16 * VTS + kkb + quad * 4];
        ((uint2*)&av0)[1] = *(const uint2*)&Vt[l16 * VTS + kkb + 16 + quad * 4];
        ((uint2*)&av1)[0] = *(const uint2*)&Vt[(16 + l16) * VTS + kkb + quad * 4];
        ((uint2*)&av1)[1] = *(const uint2*)&Vt[(16 + l16) * VTS + kkb + 16 + quad * 4];

        oT0 = __builtin_amdgcn_mfma_f32_16x16x32_bf16(av0, pf.v, oT0, 0, 0, 0);
        oT1 = __builtin_amdgcn_mfma_f32_16x16x32_bf16(av1, pf.v, oT1, 0, 0, 0);
        m_run = mnew;
    }

    float l = l_part;
    l += __shfl_xor(l, 16);
    l += __shfl_xor(l, 32);
    float invl = (l > 0.f) ? 1.f / l : 0.f;

    unsigned short* orow = o + ((size_t)(b * NSEQ + qbase + l16)) * DMODEL + h * DK;
#pragma unroll
    for (int r = 0; r < 4; r++) {
        orow[quad * 4 + r]      = f2bf(oT0[r] * invl);
        orow[16 + quad * 4 + r] = f2bf(oT1[r] * invl);
    }
}

// Final LN: out = LayerNorm(x) * gf + bf (fp32)
__global__ __launch_bounds__(256) void final_ln_kernel(
        const float* __restrict__ a,
        const float* __restrict__ g, const float* __restrict__ be,
        float* __restrict__ out) {
    int t = blockIdx.x;
    int d = threadIdx.x;
    size_t idx = (size_t)t * DMODEL + d;
    float v = a[idx];
    float s = v, s2 = v * v;
#pragma unroll
    for (int off = 32; off; off >>= 1) {
        s  += __shfl_xor(s, off);
        s2 += __shfl_xor(s2, off);
    }
    __shared__ float ws1[4], ws2[4];
    int wid = d >> 6;
    if ((d & 63) == 0) { ws1[wid] = s; ws2[wid] = s2; }
    __syncthreads();
    s  = ws1[0] + ws1[1] + ws1[2] + ws1[3];
    s2 = ws2[0] + ws2[1] + ws2[2] + ws2[3];
    float mean = s * (1.f / DMODEL);
    float var = s2 * (1.f / DMODEL) - mean * mean;
    float rstd = rsqrtf(var + 1e-5f);
    out[idx] = (v - mean) * rstd * g[d] + be[d];
}

// ---------------------------------------------------------------------------
extern "C" void kernel_launch(void* const* d_in, const int* in_sizes, int n_in,
                              void* d_out, int out_size, void* d_ws, size_t ws_size,
                              hipStream_t stream) {
    const float* input  = (const float*)d_in[0];
    const float* inputv = (const float*)d_in[1];
    const float* pos    = (const float*)d_in[2];
    const float* Wq = (const float*)d_in[3];
    const float* bq = (const float*)d_in[4];
    const float* Wk = (const float*)d_in[5];
    const float* bk = (const float*)d_in[6];
    const float* Wv = (const float*)d_in[7];
    const float* bv = (const float*)d_in[8];
    const float* Wo = (const float*)d_in[9];
    const float* bo = (const float*)d_in[10];
    const float* W1 = (const float*)d_in[11];
    const float* b1 = (const float*)d_in[12];
    const float* W2 = (const float*)d_in[13];
    const float* b2 = (const float*)d_in[14];
    const float* g1 = (const float*)d_in[15];
    const float* be1 = (const float*)d_in[16];
    const float* g2 = (const float*)d_in[17];
    const float* be2 = (const float*)d_in[18];
    const float* gf = (const float*)d_in[19];
    const float* bff = (const float*)d_in[20];
    const int* mask = (const int*)d_in[21];

    float* out = (float*)d_out;

    // Workspace layout (bytes), ~37 MB
    char* wsb = (char*)d_ws;
    float* x_f  = (float*)(wsb + ((size_t)0 << 20));                    // 8 MB
    unsigned short* x_b  = (unsigned short*)(wsb + ((size_t)8 << 20));  // 4 MB
    unsigned short* xv_b = (unsigned short*)(wsb + ((size_t)12 << 20)); // 4 MB
    unsigned short* qb_b = (unsigned short*)(wsb + ((size_t)16 << 20)); // 4 MB
    unsigned short* kb_b = (unsigned short*)(wsb + ((size_t)20 << 20)); // 4 MB
    unsigned short* vb_b = (unsigned short*)(wsb + ((size_t)24 << 20)); // 4 MB
    unsigned short* ab_b = (unsigned short*)(wsb + ((size_t)28 << 20)); // 4 MB
    unsigned short* h_b  = qb_b;  // 16 MB alias over qb..ab (dead during FFN)
    unsigned short* wqT = (unsigned short*)(wsb + ((size_t)32 << 20));
    unsigned short* wkT = wqT + (size_t)4 * 65536;
    unsigned short* wvT = wkT + (size_t)4 * 65536;
    unsigned short* woT = wvT + (size_t)4 * 65536;
    unsigned short* w1T = woT + (size_t)4 * 65536;   // 4 x 262144
    unsigned short* w2T = w1T + (size_t)4 * 262144;  // 4 x 65536
    unsigned* mbits = (unsigned*)(wsb + ((size_t)37 << 20));            // 32 KB

    const size_t TOK = (size_t)BN * DMODEL;

    // --- preconversions (4 dispatches) ---
    conv_qkvo_kernel<<<4096, 256, 0, stream>>>(Wq, Wk, Wv, Wo, wqT, wkT, wvT, woT);
    conv_w12_kernel<<<(4 * 262144 + 4 * 65536) / 256, 256, 0, stream>>>(W1, W2, w1T, w2T);
    conv_mask_kernel<<<8192 / 256, 256, 0, stream>>>(mask, mbits);
    add_pos_kernel<<<(int)((TOK + 255) / 256), 256, 0, stream>>>(
        input, inputv, pos, x_f, x_b, xv_b, (int)TOK);

    for (int i = 0; i < NLAYER; i++) {
        const unsigned short* WqT_i = wqT + (size_t)i * 65536;
        const unsigned short* WkT_i = wkT + (size_t)i * 65536;
        const unsigned short* WvT_i = wvT + (size_t)i * 65536;
        const unsigned short* WoT_i = woT + (size_t)i * 65536;
        const unsigned short* W1T_i = w1T + (size_t)i * 262144;
        const unsigned short* W2T_i = w2T + (size_t)i * 65536;

        qkv_mfma_kernel<<<dim3(6, 64), 256, 0, stream>>>(
            x_b, xv_b, WqT_i, WkT_i, WvT_i,
            bq + i * DMODEL, bk + i * DMODEL, bv + i * DMODEL,
            qb_b, kb_b, vb_b);

        attn_mfma_kernel<<<BDIM * NHEAD * 8, 256, 0, stream>>>(
            qb_b, kb_b, vb_b, ab_b, mbits, (i & 1));

        wo_ln_kernel<<<BN / 32, 128, 0, stream>>>(
            ab_b, WoT_i, bo + i * DMODEL,
            g1 + i * DMODEL, be1 + i * DMODEL, x_f, x_b);

        gemm_mfma_kernel<<<dim3(8, 64), 256, 0, stream>>>(
            x_b, W1T_i, b1 + i * DFF, h_b, BN, DMODEL, DFF, 1);

        ffn2_ln_kernel<<<(2 * BN) / 64, 128, 0, stream>>>(
            h_b, W2T_i, b2 + i * (DMODEL / 2),
            g2 + i * DMODEL, be2 + i * DMODEL, x_f, x_b);
    }

    final_ln_kernel<<<BN, DMODEL, 0, stream>>>(x_f, gf, bff, out);
}